// Round 3
// baseline (483.321 us; speedup 1.0000x reference)
//
#include <hip/hip_runtime.h>
#include <hip/hip_bf16.h>
#include <math.h>

using bf16 = __hip_bfloat16;
typedef __attribute__((ext_vector_type(8))) short short8;
typedef __attribute__((ext_vector_type(4))) float float4v;

#define BM 128
#define BN 128
#define BK 64
// NOTE: no LDS padding — global_load_lds writes (wave-uniform base + lane*16B),
// so the tile must be stored dense row-major (row stride 64 bf16 = 128 B).
// m97 reached 874 TF with this exact unpadded layout; bank conflicts are the
// free/cheap 2-way kind in the b128-read phases.

template <typename T> __device__ inline T cvt_out(float v);
template <> __device__ inline float cvt_out<float>(float v) { return v; }
template <> __device__ inline bf16 cvt_out<bf16>(float v) { return __float2bfloat16(v); }

__device__ inline void gload_lds16(const bf16* g, bf16* l) {
    __builtin_amdgcn_global_load_lds(
        (const __attribute__((address_space(1))) void*)g,
        (__attribute__((address_space(3))) void*)l, 16, 0, 0);
}

// fp32 -> bf16 bulk convert, 4 elems/thread
__global__ __launch_bounds__(256) void cvt_f32_bf16(const float* __restrict__ in,
                                                    bf16* __restrict__ out, int n) {
    int i = (blockIdx.x * blockDim.x + threadIdx.x) * 4;
    if (i < n) {
        float4 v = *(const float4*)(in + i);
        out[i + 0] = __float2bfloat16(v.x);
        out[i + 1] = __float2bfloat16(v.y);
        out[i + 2] = __float2bfloat16(v.z);
        out[i + 3] = __float2bfloat16(v.w);
    }
}

// out[m][n] = bias[n] for an (M,N) fp32 buffer; N power of two, multiple of 4.
__global__ __launch_bounds__(256) void fill_bias(float* __restrict__ out,
                                                 const float* __restrict__ bias,
                                                 int nmask, int total4) {
    int i = blockIdx.x * blockDim.x + threadIdx.x;
    if (i < total4) {
        int idx = i * 4;
        *(float4*)(out + idx) = *(const float4*)(bias + (idx & nmask));
    }
}

// C[m][n] = act( sum_k A[m][k] * W[n][k] + bias[n] )
// ACT: 0=none, 1=relu, 2=tanh. ATOMIC: split-K partial, bias pre-filled, fp32 out.
// A: (M,K) bf16 row-major. W: (N,K) bf16 row-major. Kc = K-chunk per z-block.
template <int ACT, typename OutT, bool ATOMIC>
__global__ __launch_bounds__(256) void gemm_bt(const bf16* __restrict__ A,
                                               const bf16* __restrict__ W,
                                               const float* __restrict__ bias,
                                               OutT* __restrict__ C,
                                               int M, int N, int K, int Kc) {
    __shared__ bf16 As[BM * BK];
    __shared__ bf16 Bs[BN * BK];

    const int tid = threadIdx.x;
    const int bm = blockIdx.y, bn = blockIdx.x;
    const int wave = tid >> 6, lane = tid & 63;
    const int wm = (wave >> 1) * 64, wn = (wave & 1) * 64;
    const int quad = lane >> 4, lrow = lane & 15;
    const int kbeg = blockIdx.z * Kc;

    // staging geometry: tile = 128 rows x 64 cols bf16 = 1024 chunks of 16 B.
    // chunk = t*256 + wave*64 + lane; LDS dest = chunk*16 B with the wave-uniform
    // base (t*256+wave*64)*16 B and HW-added lane*16 B. Global src = row-major.
    const int chunk_base[4] = {wave * 64, 256 + wave * 64, 512 + wave * 64, 768 + wave * 64};

    float4v acc[4][4] = {};
    const size_t arow = (size_t)(bm * BM) * K;
    const size_t brow = (size_t)(bn * BN) * K;

    for (int k0 = kbeg; k0 < kbeg + Kc; k0 += BK) {
        __syncthreads();  // protect LDS from previous iteration's readers
#pragma unroll
        for (int t = 0; t < 4; ++t) {
            int chunk = chunk_base[t] + lane;
            int row = chunk >> 3, col = (chunk & 7) * 8;
            gload_lds16(A + arow + (size_t)row * K + k0 + col, As + chunk_base[t] * 8);
            gload_lds16(W + brow + (size_t)row * K + k0 + col, Bs + chunk_base[t] * 8);
        }
        __syncthreads();  // compiler emits vmcnt(0) drain of the async loads here
#pragma unroll
        for (int kk = 0; kk < BK; kk += 32) {
            short8 af[4], bfr[4];
#pragma unroll
            for (int i = 0; i < 4; ++i)
                af[i] = *(const short8*)(As + (wm + i * 16 + lrow) * BK + kk + quad * 8);
#pragma unroll
            for (int j = 0; j < 4; ++j)
                bfr[j] = *(const short8*)(Bs + (wn + j * 16 + lrow) * BK + kk + quad * 8);
#pragma unroll
            for (int i = 0; i < 4; ++i)
#pragma unroll
                for (int j = 0; j < 4; ++j)
                    acc[i][j] = __builtin_amdgcn_mfma_f32_16x16x32_bf16(af[i], bfr[j], acc[i][j], 0, 0, 0);
        }
    }

    // epilogue: C/D layout col=lane&15, row=quad*4+reg (m89/m91-verified)
#pragma unroll
    for (int i = 0; i < 4; ++i) {
        int m0 = bm * BM + wm + i * 16 + quad * 4;
#pragma unroll
        for (int j = 0; j < 4; ++j) {
            int n = bn * BN + wn + j * 16 + lrow;
            if constexpr (ATOMIC) {
#pragma unroll
                for (int r = 0; r < 4; ++r)
                    atomicAdd((float*)&C[(size_t)(m0 + r) * N + n], acc[i][j][r]);
            } else {
                float bv = bias[n];
#pragma unroll
                for (int r = 0; r < 4; ++r) {
                    float v = acc[i][j][r] + bv;
                    if (ACT == 1) v = fmaxf(v, 0.f);
                    else if (ACT == 2) v = tanhf(v);
                    C[(size_t)(m0 + r) * N + n] = cvt_out<OutT>(v);
                }
            }
        }
    }
}

// One wave per row: power-norm -> single-tap channel + noise -> LS h_est -> ZF.
__global__ __launch_bounds__(64) void channel_kernel(const float* __restrict__ s,
                                                     const float* __restrict__ h,
                                                     const float* __restrict__ noise,
                                                     float* __restrict__ xr_f,
                                                     bf16* __restrict__ xr_b) {
    const int b = blockIdx.x, lane = threadIdx.x;
    const float* srow = s + (size_t)b * 256;

    float ss = 0.f;
#pragma unroll
    for (int t = 0; t < 4; ++t) {
        float v = srow[lane + 64 * t];
        ss += v * v;
    }
#pragma unroll
    for (int off = 32; off; off >>= 1) ss += __shfl_xor(ss, off);
    const float inv = sqrtf(128.0f) / sqrtf(ss);  // sqrt(2n*0.5) / ||s||

    const float hre = h[0], him = h[1];

    float yre[2], yim[2];
    float nre = 0.f, nim = 0.f, den = 0.f;
#pragma unroll
    for (int t = 0; t < 2; ++t) {
        int c = lane + 64 * t;
        float tr = srow[2 * c] * inv, ti = srow[2 * c + 1] * inv;
        float yr = hre * tr - him * ti + noise[(size_t)b * 256 + 2 * c];
        float yi = hre * ti + him * tr + noise[(size_t)b * 256 + 2 * c + 1];
        yre[t] = yr; yim[t] = yi;
        nre += yr * tr + yi * ti;
        nim += yi * tr - yr * ti;
        den += tr * tr + ti * ti;
    }
#pragma unroll
    for (int off = 32; off; off >>= 1) {
        nre += __shfl_xor(nre, off);
        nim += __shfl_xor(nim, off);
        den += __shfl_xor(den, off);
    }
    const float her = nre / den, hei = nim / den;
    const float d2 = her * her + hei * hei + 1e-12f;

#pragma unroll
    for (int t = 0; t < 2; ++t) {
        int c = lane + 64 * t;
        float xre = (yre[t] * her + yim[t] * hei) / d2;
        float xim = (yim[t] * her - yre[t] * hei) / d2;
        xr_f[(size_t)b * 256 + 2 * c] = xre;
        xr_f[(size_t)b * 256 + 2 * c + 1] = xim;
        xr_b[(size_t)b * 256 + 2 * c] = __float2bfloat16(xre);
        xr_b[(size_t)b * 256 + 2 * c + 1] = __float2bfloat16(xim);
    }
}

// One wave per row: h_inv = g2 @ w_rtn3^T + b_rtn3 (N=6), 3-tap complex FIR.
__global__ __launch_bounds__(64) void rtn_taps_conv(const bf16* __restrict__ g2,
                                                    const float* __restrict__ wr3,
                                                    const float* __restrict__ br3,
                                                    const float* __restrict__ xr_f,
                                                    bf16* __restrict__ xr2) {
    const int b = blockIdx.x, lane = threadIdx.x;
    const bf16* grow = g2 + (size_t)b * 1024;

    float acc[6] = {0.f, 0.f, 0.f, 0.f, 0.f, 0.f};
#pragma unroll
    for (int t = 0; t < 16; ++t) {
        int k = lane + 64 * t;
        float gv = __bfloat162float(grow[k]);
#pragma unroll
        for (int j = 0; j < 6; ++j) acc[j] += gv * wr3[j * 1024 + k];
    }
#pragma unroll
    for (int j = 0; j < 6; ++j)
#pragma unroll
        for (int off = 32; off; off >>= 1) acc[j] += __shfl_xor(acc[j], off);

    float tre[3], tim[3];
#pragma unroll
    for (int l = 0; l < 3; ++l) {
        tre[l] = acc[2 * l] + br3[2 * l];
        tim[l] = acc[2 * l + 1] + br3[2 * l + 1];
    }

    const float* xrow = xr_f + (size_t)b * 256;
#pragma unroll
    for (int t = 0; t < 2; ++t) {
        int c = lane + 64 * t;
        float ore = 0.f, oim = 0.f;
#pragma unroll
        for (int l = 0; l < 3; ++l) {
            int cc = c - l;
            if (cc >= 0) {
                float xre = xrow[2 * cc], xim = xrow[2 * cc + 1];
                ore += tre[l] * xre - tim[l] * xim;
                oim += tre[l] * xim + tim[l] * xre;
            }
        }
        xr2[(size_t)b * 256 + 2 * c] = __float2bfloat16(ore);
        xr2[(size_t)b * 256 + 2 * c + 1] = __float2bfloat16(oim);
    }
}

extern "C" void kernel_launch(void* const* d_in, const int* in_sizes, int n_in,
                              void* d_out, int out_size, void* d_ws, size_t ws_size,
                              hipStream_t stream) {
    constexpr int B = 8192, D_IN = 512, H1 = 4096, CH = 256, HR = 1024, H2 = 4096, DOUT = 512;

    const float* x   = (const float*)d_in[0];
    const float* w1  = (const float*)d_in[1];
    const float* b1  = (const float*)d_in[2];
    const float* w2  = (const float*)d_in[3];
    const float* b2  = (const float*)d_in[4];
    const float* wr1 = (const float*)d_in[5];
    const float* br1 = (const float*)d_in[6];
    const float* wr2 = (const float*)d_in[7];
    const float* br2 = (const float*)d_in[8];
    const float* wr3 = (const float*)d_in[9];
    const float* br3 = (const float*)d_in[10];
    const float* w3  = (const float*)d_in[11];
    const float* b3  = (const float*)d_in[12];
    const float* w4  = (const float*)d_in[13];
    const float* b4  = (const float*)d_in[14];
    const float* h   = (const float*)d_in[15];
    const float* noise = (const float*)d_in[16];

    // ---- workspace layout (bytes) ----
    char* ws = (char*)d_ws;
    bf16*  a    = (bf16*)(ws + 0);          // 64 MB: GEMM1 out; later: g1 | tbuf
    bf16*  g1   = (bf16*)(ws + 0);          // 16 MB (a dead after GEMM2)
    bf16*  g2   = (bf16*)(ws + 16777216);   // 16 MB
    bf16*  tbuf = (bf16*)(ws + 0);          // 64 MB (g1/g2 dead after rtn_taps_conv)
    bf16*  xB   = (bf16*)(ws + 67108864);               // 8 MB  bf16(x)
    float* sF   = (float*)(ws + 75497472);              // 8 MB
    float* xrF  = (float*)(ws + 83886080);              // 8 MB
    bf16*  xrB  = (bf16*)(ws + 92274688);               // 4 MB
    bf16*  xr2  = (bf16*)(ws + 96468992);               // 4 MB
    bf16*  w1B  = (bf16*)(ws + 100663296);              // 4 MB
    bf16*  w2B  = (bf16*)(ws + 104857600);              // 2 MB
    bf16*  wr1B = (bf16*)(ws + 106954752);              // 0.5 MB
    bf16*  wr2B = (bf16*)(ws + 107479040);              // 2 MB
    bf16*  w3B  = (bf16*)(ws + 109576192);              // 2 MB
    bf16*  w4B  = (bf16*)(ws + 111673344);              // 4 MB -> ends ~115.9 MB

    dim3 blk(256);

    // ---- fp32 -> bf16 conversions ----
    auto cvt = [&](const float* src, bf16* dst, int n) {
        cvt_f32_bf16<<<(n / 4 + 255) / 256, blk, 0, stream>>>(src, dst, n);
    };
    cvt(x,   xB,   B * D_IN);
    cvt(w1,  w1B,  H1 * D_IN);
    cvt(w2,  w2B,  CH * H1);
    cvt(wr1, wr1B, HR * CH);
    cvt(wr2, wr2B, HR * HR);
    cvt(w3,  w3B,  H2 * CH);
    cvt(w4,  w4B,  DOUT * H2);

    // ---- encoder ----
    gemm_bt<1, bf16, false><<<dim3(H1 / BN, B / BM, 1), blk, 0, stream>>>(
        xB, w1B, b1, a, B, H1, D_IN, D_IN);
    // GEMM2 split-K=8 (N=256 -> only 128 tiles; split for occupancy)
    fill_bias<<<(B * CH / 4 + 255) / 256, blk, 0, stream>>>(sF, b2, CH - 1, B * CH / 4);
    gemm_bt<0, float, true><<<dim3(CH / BN, B / BM, 8), blk, 0, stream>>>(
        a, w2B, nullptr, sF, B, CH, H1, H1 / 8);
    // ---- channel + ZF (fp32) ----
    channel_kernel<<<B, 64, 0, stream>>>(sF, h, noise, xrF, xrB);
    // ---- RTN ----
    gemm_bt<2, bf16, false><<<dim3(HR / BN, B / BM, 1), blk, 0, stream>>>(
        xrB, wr1B, br1, g1, B, HR, CH, CH);
    gemm_bt<2, bf16, false><<<dim3(HR / BN, B / BM, 1), blk, 0, stream>>>(
        g1, wr2B, br2, g2, B, HR, HR, HR);
    rtn_taps_conv<<<B, 64, 0, stream>>>(g2, wr3, br3, xrF, xr2);
    // ---- decoder ----
    gemm_bt<1, bf16, false><<<dim3(H2 / BN, B / BM, 1), blk, 0, stream>>>(
        xr2, w3B, b3, tbuf, B, H2, CH, CH);
    // GEMM7 split-K=4 (N=512 -> only 256 tiles; split for occupancy)
    fill_bias<<<(B * DOUT / 4 + 255) / 256, blk, 0, stream>>>(
        (float*)d_out, b4, DOUT - 1, B * DOUT / 4);
    gemm_bt<0, float, true><<<dim3(DOUT / BN, B / BM, 4), blk, 0, stream>>>(
        tbuf, w4B, nullptr, (float*)d_out, B, DOUT, H2, H2 / 4);
}

// Round 4
// 442.130 us; speedup vs baseline: 1.0932x; 1.0932x over previous
//
#include <hip/hip_runtime.h>
#include <hip/hip_bf16.h>
#include <math.h>

using bf16 = __hip_bfloat16;
typedef __attribute__((ext_vector_type(8))) short short8;
typedef __attribute__((ext_vector_type(4))) float float4v;

template <typename T> __device__ inline T cvt_out(float v);
template <> __device__ inline float cvt_out<float>(float v) { return v; }
template <> __device__ inline bf16 cvt_out<bf16>(float v) { return __float2bfloat16(v); }

__device__ inline void gload_lds16(const bf16* g, bf16* l) {
    __builtin_amdgcn_global_load_lds(
        (const __attribute__((address_space(1))) void*)g,
        (__attribute__((address_space(3))) void*)l, 16, 0, 0);
}

// ---- fused fp32->bf16 convert for x + 6 weights, one launch ----
struct CvtPack {
    const float* src[7];
    bf16* dst[7];
    int end[7];   // cumulative element ends
};

__global__ __launch_bounds__(256) void cvt_all(CvtPack p) {
    int e = (blockIdx.x * 256 + threadIdx.x) * 4;
    int start = 0;
#pragma unroll
    for (int s = 0; s < 7; ++s) {
        if (e < p.end[s]) {
            int off = e - start;
            float4 v = *(const float4*)(p.src[s] + off);
            bf16* d = p.dst[s] + off;
            d[0] = __float2bfloat16(v.x);
            d[1] = __float2bfloat16(v.y);
            d[2] = __float2bfloat16(v.z);
            d[3] = __float2bfloat16(v.w);
            return;
        }
        start = p.end[s];
    }
}

// C[m][n] = act( sum_k A[m][k] * W[n][k] + bias[n] )
// ACT: 0=none, 1=relu, 2=tanh.
// Tile = (32*WMT) x (32*WNT), 4 waves in a 2x2 grid, each wave (16*WMT)x(16*WNT).
// BKT = K-tile. LDS stored dense row-major (global_load_lds contract:
// wave-uniform base + lane*16B — no padding allowed).
template <int ACT, typename OutT, int WMT, int WNT, int BKT>
__global__ __launch_bounds__(256) void gemm_bt(const bf16* __restrict__ A,
                                               const bf16* __restrict__ W,
                                               const float* __restrict__ bias,
                                               OutT* __restrict__ C,
                                               int M, int N, int K) {
    constexpr int TBM = 32 * WMT;
    constexpr int TBN = 32 * WNT;
    constexpr int CPR = BKT / 8;          // 16B chunks per tile row
    constexpr int CA = TBM * CPR;         // total A chunks (multiple of 256)
    constexpr int CB = TBN * CPR;

    __shared__ bf16 As[TBM * BKT];
    __shared__ bf16 Bs[TBN * BKT];

    const int tid = threadIdx.x;
    const int bm = blockIdx.y, bn = blockIdx.x;
    const int wave = tid >> 6, lane = tid & 63;
    const int wm = (wave >> 1) * (16 * WMT), wn = (wave & 1) * (16 * WNT);
    const int quad = lane >> 4, lrow = lane & 15;

    float4v acc[WMT][WNT] = {};
    const size_t arow = (size_t)(bm * TBM) * K;
    const size_t brow = (size_t)(bn * TBN) * K;

    for (int k0 = 0; k0 < K; k0 += BKT) {
        __syncthreads();  // protect LDS from previous iteration's readers
#pragma unroll
        for (int t = 0; t < CA / 256; ++t) {
            int base = t * 256 + wave * 64;        // wave-uniform
            int c = base + lane;
            int row = c / CPR, col = (c % CPR) * 8;
            gload_lds16(A + arow + (size_t)row * K + k0 + col, As + base * 8);
        }
#pragma unroll
        for (int t = 0; t < CB / 256; ++t) {
            int base = t * 256 + wave * 64;
            int c = base + lane;
            int row = c / CPR, col = (c % CPR) * 8;
            gload_lds16(W + brow + (size_t)row * K + k0 + col, Bs + base * 8);
        }
        __syncthreads();  // drains the async loads (vmcnt(0)) + barrier
#pragma unroll
        for (int kk = 0; kk < BKT; kk += 32) {
            short8 af[WMT], bfr[WNT];
#pragma unroll
            for (int i = 0; i < WMT; ++i)
                af[i] = *(const short8*)(As + (wm + i * 16 + lrow) * BKT + kk + quad * 8);
#pragma unroll
            for (int j = 0; j < WNT; ++j)
                bfr[j] = *(const short8*)(Bs + (wn + j * 16 + lrow) * BKT + kk + quad * 8);
#pragma unroll
            for (int i = 0; i < WMT; ++i)
#pragma unroll
                for (int j = 0; j < WNT; ++j)
                    acc[i][j] = __builtin_amdgcn_mfma_f32_16x16x32_bf16(af[i], bfr[j], acc[i][j], 0, 0, 0);
        }
    }

    // epilogue: C/D layout col=lane&15, row=quad*4+reg (m89/m91-verified)
#pragma unroll
    for (int i = 0; i < WMT; ++i) {
        int m0 = bm * TBM + wm + i * 16 + quad * 4;
#pragma unroll
        for (int j = 0; j < WNT; ++j) {
            int n = bn * TBN + wn + j * 16 + lrow;
            float bv = bias[n];
#pragma unroll
            for (int r = 0; r < 4; ++r) {
                float v = acc[i][j][r] + bv;
                if (ACT == 1) v = fmaxf(v, 0.f);
                else if (ACT == 2) v = tanhf(v);
                C[(size_t)(m0 + r) * N + n] = cvt_out<OutT>(v);
            }
        }
    }
}

// One wave per row: power-norm -> single-tap channel + noise -> LS h_est -> ZF.
__global__ __launch_bounds__(64) void channel_kernel(const float* __restrict__ s,
                                                     const float* __restrict__ h,
                                                     const float* __restrict__ noise,
                                                     float* __restrict__ xr_f,
                                                     bf16* __restrict__ xr_b) {
    const int b = blockIdx.x, lane = threadIdx.x;
    const float* srow = s + (size_t)b * 256;

    float ss = 0.f;
#pragma unroll
    for (int t = 0; t < 4; ++t) {
        float v = srow[lane + 64 * t];
        ss += v * v;
    }
#pragma unroll
    for (int off = 32; off; off >>= 1) ss += __shfl_xor(ss, off);
    const float inv = sqrtf(128.0f) / sqrtf(ss);  // sqrt(2n*0.5) / ||s||

    const float hre = h[0], him = h[1];

    float yre[2], yim[2];
    float nre = 0.f, nim = 0.f, den = 0.f;
#pragma unroll
    for (int t = 0; t < 2; ++t) {
        int c = lane + 64 * t;
        float tr = srow[2 * c] * inv, ti = srow[2 * c + 1] * inv;
        float yr = hre * tr - him * ti + noise[(size_t)b * 256 + 2 * c];
        float yi = hre * ti + him * tr + noise[(size_t)b * 256 + 2 * c + 1];
        yre[t] = yr; yim[t] = yi;
        nre += yr * tr + yi * ti;
        nim += yi * tr - yr * ti;
        den += tr * tr + ti * ti;
    }
#pragma unroll
    for (int off = 32; off; off >>= 1) {
        nre += __shfl_xor(nre, off);
        nim += __shfl_xor(nim, off);
        den += __shfl_xor(den, off);
    }
    const float her = nre / den, hei = nim / den;
    const float d2 = her * her + hei * hei + 1e-12f;

#pragma unroll
    for (int t = 0; t < 2; ++t) {
        int c = lane + 64 * t;
        float xre = (yre[t] * her + yim[t] * hei) / d2;
        float xim = (yim[t] * her - yre[t] * hei) / d2;
        xr_f[(size_t)b * 256 + 2 * c] = xre;
        xr_f[(size_t)b * 256 + 2 * c + 1] = xim;
        xr_b[(size_t)b * 256 + 2 * c] = __float2bfloat16(xre);
        xr_b[(size_t)b * 256 + 2 * c + 1] = __float2bfloat16(xim);
    }
}

// One wave per row: h_inv = g2 @ w_rtn3^T + b_rtn3 (N=6), 3-tap complex FIR.
__global__ __launch_bounds__(64) void rtn_taps_conv(const bf16* __restrict__ g2,
                                                    const float* __restrict__ wr3,
                                                    const float* __restrict__ br3,
                                                    const float* __restrict__ xr_f,
                                                    bf16* __restrict__ xr2) {
    const int b = blockIdx.x, lane = threadIdx.x;
    const bf16* grow = g2 + (size_t)b * 1024;

    float acc[6] = {0.f, 0.f, 0.f, 0.f, 0.f, 0.f};
#pragma unroll
    for (int t = 0; t < 16; ++t) {
        int k = lane + 64 * t;
        float gv = __bfloat162float(grow[k]);
#pragma unroll
        for (int j = 0; j < 6; ++j) acc[j] += gv * wr3[j * 1024 + k];
    }
#pragma unroll
    for (int j = 0; j < 6; ++j)
#pragma unroll
        for (int off = 32; off; off >>= 1) acc[j] += __shfl_xor(acc[j], off);

    float tre[3], tim[3];
#pragma unroll
    for (int l = 0; l < 3; ++l) {
        tre[l] = acc[2 * l] + br3[2 * l];
        tim[l] = acc[2 * l + 1] + br3[2 * l + 1];
    }

    const float* xrow = xr_f + (size_t)b * 256;
#pragma unroll
    for (int t = 0; t < 2; ++t) {
        int c = lane + 64 * t;
        float ore = 0.f, oim = 0.f;
#pragma unroll
        for (int l = 0; l < 3; ++l) {
            int cc = c - l;
            if (cc >= 0) {
                float xre = xrow[2 * cc], xim = xrow[2 * cc + 1];
                ore += tre[l] * xre - tim[l] * xim;
                oim += tre[l] * xim + tim[l] * xre;
            }
        }
        xr2[(size_t)b * 256 + 2 * c] = __float2bfloat16(ore);
        xr2[(size_t)b * 256 + 2 * c + 1] = __float2bfloat16(oim);
    }
}

extern "C" void kernel_launch(void* const* d_in, const int* in_sizes, int n_in,
                              void* d_out, int out_size, void* d_ws, size_t ws_size,
                              hipStream_t stream) {
    constexpr int B = 8192, D_IN = 512, H1 = 4096, CH = 256, HR = 1024, H2 = 4096, DOUT = 512;

    const float* x   = (const float*)d_in[0];
    const float* w1  = (const float*)d_in[1];
    const float* b1  = (const float*)d_in[2];
    const float* w2  = (const float*)d_in[3];
    const float* b2  = (const float*)d_in[4];
    const float* wr1 = (const float*)d_in[5];
    const float* br1 = (const float*)d_in[6];
    const float* wr2 = (const float*)d_in[7];
    const float* br2 = (const float*)d_in[8];
    const float* wr3 = (const float*)d_in[9];
    const float* br3 = (const float*)d_in[10];
    const float* w3  = (const float*)d_in[11];
    const float* b3  = (const float*)d_in[12];
    const float* w4  = (const float*)d_in[13];
    const float* b4  = (const float*)d_in[14];
    const float* h   = (const float*)d_in[15];
    const float* noise = (const float*)d_in[16];

    // ---- workspace layout (bytes), peak ~116 MB (fits round-2-proven budget) ----
    char* ws = (char*)d_ws;
    bf16*  a    = (bf16*)(ws + 0);          // 64 MB: GEMM1 out; later: g1 | tbuf
    bf16*  g1   = (bf16*)(ws + 0);          // 16 MB (a dead after GEMM2)
    bf16*  g2   = (bf16*)(ws + 16777216);   // 16 MB
    bf16*  tbuf = (bf16*)(ws + 0);          // 64 MB (g1/g2 dead after rtn_taps_conv)
    bf16*  xB   = (bf16*)(ws + 67108864);               // 8 MB  bf16(x)
    float* sF   = (float*)(ws + 75497472);              // 8 MB
    float* xrF  = (float*)(ws + 83886080);              // 8 MB
    bf16*  xrB  = (bf16*)(ws + 92274688);               // 4 MB
    bf16*  xr2  = (bf16*)(ws + 96468992);               // 4 MB
    bf16*  w1B  = (bf16*)(ws + 100663296);              // 4 MB
    bf16*  w2B  = (bf16*)(ws + 104857600);              // 2 MB
    bf16*  wr1B = (bf16*)(ws + 106954752);              // 0.5 MB
    bf16*  wr2B = (bf16*)(ws + 107479040);              // 2 MB
    bf16*  w3B  = (bf16*)(ws + 109576192);              // 2 MB
    bf16*  w4B  = (bf16*)(ws + 111673344);              // 4 MB -> ends ~115.9 MB

    dim3 blk(256);

    // ---- single fused fp32->bf16 convert ----
    CvtPack p;
    const float* srcs[7] = {x, w1, w2, wr1, wr2, w3, w4};
    bf16* dsts[7] = {xB, w1B, w2B, wr1B, wr2B, w3B, w4B};
    int ns[7] = {B * D_IN, H1 * D_IN, CH * H1, HR * CH, HR * HR, H2 * CH, DOUT * H2};
    int cum = 0;
    for (int i = 0; i < 7; ++i) { p.src[i] = srcs[i]; p.dst[i] = dsts[i]; cum += ns[i]; p.end[i] = cum; }
    cvt_all<<<(cum / 4 + 255) / 256, blk, 0, stream>>>(p);

    // ---- encoder ----
    // G1: 128x128, BK=64, grid 32x64=2048
    gemm_bt<1, bf16, 4, 4, 64><<<dim3(H1 / 128, B / 128), blk, 0, stream>>>(
        xB, w1B, b1, a, B, H1, D_IN);
    // G2: N=256 skinny -> 64x64 tile, BK=128, grid 4x128=512 (2 blocks/CU)
    gemm_bt<0, float, 2, 2, 128><<<dim3(CH / 64, B / 64), blk, 0, stream>>>(
        a, w2B, b2, sF, B, CH, H1);
    // ---- channel + ZF (fp32) ----
    channel_kernel<<<B, 64, 0, stream>>>(sF, h, noise, xrF, xrB);
    // ---- RTN ----
    // G3: 128x64, BK=64, grid 16x64=1024 (4 blocks/CU)
    gemm_bt<2, bf16, 4, 2, 64><<<dim3(HR / 64, B / 128), blk, 0, stream>>>(
        xrB, wr1B, br1, g1, B, HR, CH);
    // G4: 128x64, BK=64, grid 16x64=1024
    gemm_bt<2, bf16, 4, 2, 64><<<dim3(HR / 64, B / 128), blk, 0, stream>>>(
        g1, wr2B, br2, g2, B, HR, HR);
    rtn_taps_conv<<<B, 64, 0, stream>>>(g2, wr3, br3, xrF, xr2);
    // ---- decoder ----
    // G5: 128x128, BK=64, grid 32x64=2048
    gemm_bt<1, bf16, 4, 4, 64><<<dim3(H2 / 128, B / 128), blk, 0, stream>>>(
        xr2, w3B, b3, tbuf, B, H2, CH);
    // G6: N=512 skinny -> 128x64 tile, BK=128, grid 8x64=512 (2 blocks/CU)
    gemm_bt<0, float, 4, 2, 128><<<dim3(DOUT / 64, B / 128), blk, 0, stream>>>(
        tbuf, w4B, b4, (float*)d_out, B, DOUT, H2);
}

// Round 5
// 435.563 us; speedup vs baseline: 1.1096x; 1.0151x over previous
//
#include <hip/hip_runtime.h>
#include <hip/hip_bf16.h>
#include <math.h>

using bf16 = __hip_bfloat16;
typedef __attribute__((ext_vector_type(8))) short short8;
typedef __attribute__((ext_vector_type(4))) float float4v;

template <typename T> __device__ inline T cvt_out(float v);
template <> __device__ inline float cvt_out<float>(float v) { return v; }
template <> __device__ inline bf16 cvt_out<bf16>(float v) { return __float2bfloat16(v); }

__device__ inline void gload_lds16(const bf16* g, bf16* l) {
    __builtin_amdgcn_global_load_lds(
        (const __attribute__((address_space(1))) void*)g,
        (__attribute__((address_space(3))) void*)l, 16, 0, 0);
}

// ---- fused fp32->bf16 convert for x + 6 weights, one launch ----
struct CvtPack {
    const float* src[7];
    bf16* dst[7];
    int end[7];   // cumulative element ends
};

__global__ __launch_bounds__(256) void cvt_all(CvtPack p) {
    int e = (blockIdx.x * 256 + threadIdx.x) * 4;
    int start = 0;
#pragma unroll
    for (int s = 0; s < 7; ++s) {
        if (e < p.end[s]) {
            int off = e - start;
            float4 v = *(const float4*)(p.src[s] + off);
            bf16* d = p.dst[s] + off;
            d[0] = __float2bfloat16(v.x);
            d[1] = __float2bfloat16(v.y);
            d[2] = __float2bfloat16(v.z);
            d[3] = __float2bfloat16(v.w);
            return;
        }
        start = p.end[s];
    }
}

// C[m][n] = act( sum_k A[m][k] * W[n][k] + bias[n] )
// ACT: 0=none, 1=relu, 2=tanh.
// Tile = (32*WMT) x (32*WNT), 4 waves 2x2. 1D grid of nbm*nbn blocks with an
// XCD-aware swizzle: all bn-tiles sharing one bm (same A rows) land on ONE XCD
// (xcd = blockIdx % 8 round-robin heuristic) at consecutive slots -> A stripe
// fetched into a single L2 and reused by its nbn co-resident readers.
template <int ACT, typename OutT, int WMT, int WNT, int BKT>
__global__ __launch_bounds__(256) void gemm_bt(const bf16* __restrict__ A,
                                               const bf16* __restrict__ W,
                                               const float* __restrict__ bias,
                                               OutT* __restrict__ C,
                                               int M, int N, int K,
                                               int nbn) {
    constexpr int TBM = 32 * WMT;
    constexpr int TBN = 32 * WNT;
    constexpr int CPR = BKT / 8;          // 16B chunks per tile row
    constexpr int CA = TBM * CPR;         // total A chunks (multiple of 256)
    constexpr int CB = TBN * CPR;

    __shared__ bf16 As[TBM * BKT];
    __shared__ bf16 Bs[TBN * BKT];

    const int bi = blockIdx.x;
    const int xcd = bi & 7, t = bi >> 3;
    const int bn = t % nbn;
    const int bm = xcd + 8 * (t / nbn);   // bm % 8 == xcd for all bn of this bm

    const int tid = threadIdx.x;
    const int wave = tid >> 6, lane = tid & 63;
    const int wm = (wave >> 1) * (16 * WMT), wn = (wave & 1) * (16 * WNT);
    const int quad = lane >> 4, lrow = lane & 15;

    float4v acc[WMT][WNT] = {};
    const size_t arow = (size_t)(bm * TBM) * K;
    const size_t brow = (size_t)(bn * TBN) * K;

    for (int k0 = 0; k0 < K; k0 += BKT) {
        __syncthreads();  // protect LDS from previous iteration's readers
#pragma unroll
        for (int tt = 0; tt < CA / 256; ++tt) {
            int base = tt * 256 + wave * 64;       // wave-uniform
            int c = base + lane;
            int row = c / CPR, col = (c % CPR) * 8;
            gload_lds16(A + arow + (size_t)row * K + k0 + col, As + base * 8);
        }
#pragma unroll
        for (int tt = 0; tt < CB / 256; ++tt) {
            int base = tt * 256 + wave * 64;
            int c = base + lane;
            int row = c / CPR, col = (c % CPR) * 8;
            gload_lds16(W + brow + (size_t)row * K + k0 + col, Bs + base * 8);
        }
        __syncthreads();  // drains the async loads (vmcnt(0)) + barrier
#pragma unroll
        for (int kk = 0; kk < BKT; kk += 32) {
            short8 af[WMT], bfr[WNT];
#pragma unroll
            for (int i = 0; i < WMT; ++i)
                af[i] = *(const short8*)(As + (wm + i * 16 + lrow) * BKT + kk + quad * 8);
#pragma unroll
            for (int j = 0; j < WNT; ++j)
                bfr[j] = *(const short8*)(Bs + (wn + j * 16 + lrow) * BKT + kk + quad * 8);
#pragma unroll
            for (int i = 0; i < WMT; ++i)
#pragma unroll
                for (int j = 0; j < WNT; ++j)
                    acc[i][j] = __builtin_amdgcn_mfma_f32_16x16x32_bf16(af[i], bfr[j], acc[i][j], 0, 0, 0);
        }
    }

    // epilogue: C/D layout col=lane&15, row=quad*4+reg (m89/m91-verified)
#pragma unroll
    for (int i = 0; i < WMT; ++i) {
        int m0 = bm * TBM + wm + i * 16 + quad * 4;
#pragma unroll
        for (int j = 0; j < WNT; ++j) {
            int n = bn * TBN + wn + j * 16 + lrow;
            float bv = bias[n];
#pragma unroll
            for (int r = 0; r < 4; ++r) {
                float v = acc[i][j][r] + bv;
                if (ACT == 1) v = fmaxf(v, 0.f);
                else if (ACT == 2) v = tanhf(v);
                C[(size_t)(m0 + r) * N + n] = cvt_out<OutT>(v);
            }
        }
    }
}

// One wave per row: power-norm -> single-tap channel + noise -> LS h_est -> ZF.
__global__ __launch_bounds__(64) void channel_kernel(const float* __restrict__ s,
                                                     const float* __restrict__ h,
                                                     const float* __restrict__ noise,
                                                     float* __restrict__ xr_f,
                                                     bf16* __restrict__ xr_b) {
    const int b = blockIdx.x, lane = threadIdx.x;
    const float* srow = s + (size_t)b * 256;

    float ss = 0.f;
#pragma unroll
    for (int t = 0; t < 4; ++t) {
        float v = srow[lane + 64 * t];
        ss += v * v;
    }
#pragma unroll
    for (int off = 32; off; off >>= 1) ss += __shfl_xor(ss, off);
    const float inv = sqrtf(128.0f) / sqrtf(ss);  // sqrt(2n*0.5) / ||s||

    const float hre = h[0], him = h[1];

    float yre[2], yim[2];
    float nre = 0.f, nim = 0.f, den = 0.f;
#pragma unroll
    for (int t = 0; t < 2; ++t) {
        int c = lane + 64 * t;
        float tr = srow[2 * c] * inv, ti = srow[2 * c + 1] * inv;
        float yr = hre * tr - him * ti + noise[(size_t)b * 256 + 2 * c];
        float yi = hre * ti + him * tr + noise[(size_t)b * 256 + 2 * c + 1];
        yre[t] = yr; yim[t] = yi;
        nre += yr * tr + yi * ti;
        nim += yi * tr - yr * ti;
        den += tr * tr + ti * ti;
    }
#pragma unroll
    for (int off = 32; off; off >>= 1) {
        nre += __shfl_xor(nre, off);
        nim += __shfl_xor(nim, off);
        den += __shfl_xor(den, off);
    }
    const float her = nre / den, hei = nim / den;
    const float d2 = her * her + hei * hei + 1e-12f;

#pragma unroll
    for (int t = 0; t < 2; ++t) {
        int c = lane + 64 * t;
        float xre = (yre[t] * her + yim[t] * hei) / d2;
        float xim = (yim[t] * her - yre[t] * hei) / d2;
        xr_f[(size_t)b * 256 + 2 * c] = xre;
        xr_f[(size_t)b * 256 + 2 * c + 1] = xim;
        xr_b[(size_t)b * 256 + 2 * c] = __float2bfloat16(xre);
        xr_b[(size_t)b * 256 + 2 * c + 1] = __float2bfloat16(xim);
    }
}

// One wave per row: h_inv = g2 @ w_rtn3^T + b_rtn3 (N=6), 3-tap complex FIR.
__global__ __launch_bounds__(64) void rtn_taps_conv(const bf16* __restrict__ g2,
                                                    const float* __restrict__ wr3,
                                                    const float* __restrict__ br3,
                                                    const float* __restrict__ xr_f,
                                                    bf16* __restrict__ xr2) {
    const int b = blockIdx.x, lane = threadIdx.x;
    const bf16* grow = g2 + (size_t)b * 1024;

    float acc[6] = {0.f, 0.f, 0.f, 0.f, 0.f, 0.f};
#pragma unroll
    for (int t = 0; t < 16; ++t) {
        int k = lane + 64 * t;
        float gv = __bfloat162float(grow[k]);
#pragma unroll
        for (int j = 0; j < 6; ++j) acc[j] += gv * wr3[j * 1024 + k];
    }
#pragma unroll
    for (int j = 0; j < 6; ++j)
#pragma unroll
        for (int off = 32; off; off >>= 1) acc[j] += __shfl_xor(acc[j], off);

    float tre[3], tim[3];
#pragma unroll
    for (int l = 0; l < 3; ++l) {
        tre[l] = acc[2 * l] + br3[2 * l];
        tim[l] = acc[2 * l + 1] + br3[2 * l + 1];
    }

    const float* xrow = xr_f + (size_t)b * 256;
#pragma unroll
    for (int t = 0; t < 2; ++t) {
        int c = lane + 64 * t;
        float ore = 0.f, oim = 0.f;
#pragma unroll
        for (int l = 0; l < 3; ++l) {
            int cc = c - l;
            if (cc >= 0) {
                float xre = xrow[2 * cc], xim = xrow[2 * cc + 1];
                ore += tre[l] * xre - tim[l] * xim;
                oim += tre[l] * xim + tim[l] * xre;
            }
        }
        xr2[(size_t)b * 256 + 2 * c] = __float2bfloat16(ore);
        xr2[(size_t)b * 256 + 2 * c + 1] = __float2bfloat16(oim);
    }
}

extern "C" void kernel_launch(void* const* d_in, const int* in_sizes, int n_in,
                              void* d_out, int out_size, void* d_ws, size_t ws_size,
                              hipStream_t stream) {
    constexpr int B = 8192, D_IN = 512, H1 = 4096, CH = 256, HR = 1024, H2 = 4096, DOUT = 512;

    const float* x   = (const float*)d_in[0];
    const float* w1  = (const float*)d_in[1];
    const float* b1  = (const float*)d_in[2];
    const float* w2  = (const float*)d_in[3];
    const float* b2  = (const float*)d_in[4];
    const float* wr1 = (const float*)d_in[5];
    const float* br1 = (const float*)d_in[6];
    const float* wr2 = (const float*)d_in[7];
    const float* br2 = (const float*)d_in[8];
    const float* wr3 = (const float*)d_in[9];
    const float* br3 = (const float*)d_in[10];
    const float* w3  = (const float*)d_in[11];
    const float* b3  = (const float*)d_in[12];
    const float* w4  = (const float*)d_in[13];
    const float* b4  = (const float*)d_in[14];
    const float* h   = (const float*)d_in[15];
    const float* noise = (const float*)d_in[16];

    // ---- workspace layout (bytes), peak ~116 MB ----
    char* ws = (char*)d_ws;
    bf16*  a    = (bf16*)(ws + 0);          // 64 MB: GEMM1 out; later: g1 | tbuf
    bf16*  g1   = (bf16*)(ws + 0);          // 16 MB (a dead after GEMM2)
    bf16*  g2   = (bf16*)(ws + 16777216);   // 16 MB
    bf16*  tbuf = (bf16*)(ws + 0);          // 64 MB (g1/g2 dead after rtn_taps_conv)
    bf16*  xB   = (bf16*)(ws + 67108864);               // 8 MB  bf16(x)
    float* sF   = (float*)(ws + 75497472);              // 8 MB
    float* xrF  = (float*)(ws + 83886080);              // 8 MB
    bf16*  xrB  = (bf16*)(ws + 92274688);               // 4 MB
    bf16*  xr2  = (bf16*)(ws + 96468992);               // 4 MB
    bf16*  w1B  = (bf16*)(ws + 100663296);              // 4 MB
    bf16*  w2B  = (bf16*)(ws + 104857600);              // 2 MB
    bf16*  wr1B = (bf16*)(ws + 106954752);              // 0.5 MB
    bf16*  wr2B = (bf16*)(ws + 107479040);              // 2 MB
    bf16*  w3B  = (bf16*)(ws + 109576192);              // 2 MB
    bf16*  w4B  = (bf16*)(ws + 111673344);              // 4 MB -> ends ~115.9 MB

    dim3 blk(256);

    // ---- single fused fp32->bf16 convert ----
    CvtPack p;
    const float* srcs[7] = {x, w1, w2, wr1, wr2, w3, w4};
    bf16* dsts[7] = {xB, w1B, w2B, wr1B, wr2B, w3B, w4B};
    int ns[7] = {B * D_IN, H1 * D_IN, CH * H1, HR * CH, HR * HR, H2 * CH, DOUT * H2};
    int cum = 0;
    for (int i = 0; i < 7; ++i) { p.src[i] = srcs[i]; p.dst[i] = dsts[i]; cum += ns[i]; p.end[i] = cum; }
    cvt_all<<<(cum / 4 + 255) / 256, blk, 0, stream>>>(p);

    // ---- encoder ----
    // G1: 128x128, BK=64, nbm=64, nbn=32
    gemm_bt<1, bf16, 4, 4, 64><<<64 * 32, blk, 0, stream>>>(
        xB, w1B, b1, a, B, H1, D_IN, 32);
    // G2: 64x64, BK=128, nbm=128, nbn=4 (A=64 MB: swizzle kills x4 over-fetch)
    gemm_bt<0, float, 2, 2, 128><<<128 * 4, blk, 0, stream>>>(
        a, w2B, b2, sF, B, CH, H1, 4);
    // ---- channel + ZF (fp32) ----
    channel_kernel<<<B, 64, 0, stream>>>(sF, h, noise, xrF, xrB);
    // ---- RTN ----
    // G3: 128x64, BK=64, nbm=64, nbn=16
    gemm_bt<2, bf16, 4, 2, 64><<<64 * 16, blk, 0, stream>>>(
        xrB, wr1B, br1, g1, B, HR, CH, 16);
    // G4: 128x64, BK=64, nbm=64, nbn=16 (A=16 MB: swizzle kills x16 over-fetch)
    gemm_bt<2, bf16, 4, 2, 64><<<64 * 16, blk, 0, stream>>>(
        g1, wr2B, br2, g2, B, HR, HR, 16);
    rtn_taps_conv<<<B, 64, 0, stream>>>(g2, wr3, br3, xrF, xr2);
    // ---- decoder ----
    // G5: 128x128, BK=64, nbm=64, nbn=32
    gemm_bt<1, bf16, 4, 4, 64><<<64 * 32, blk, 0, stream>>>(
        xr2, w3B, b3, tbuf, B, H2, CH, 32);
    // G6: 128x64, BK=128, nbm=64, nbn=8 (A=64 MB: swizzle kills x8 over-fetch)
    gemm_bt<0, float, 4, 2, 128><<<64 * 8, blk, 0, stream>>>(
        tbuf, w4B, b4, (float*)d_out, B, DOUT, H2, 8);
}

// Round 7
// 414.791 us; speedup vs baseline: 1.1652x; 1.0501x over previous
//
#include <hip/hip_runtime.h>
#include <hip/hip_bf16.h>
#include <math.h>

using bf16 = __hip_bfloat16;
typedef __attribute__((ext_vector_type(8))) short short8;
typedef __attribute__((ext_vector_type(4))) float float4v;

template <typename T> __device__ inline T cvt_out(float v);
template <> __device__ inline float cvt_out<float>(float v) { return v; }
template <> __device__ inline bf16 cvt_out<bf16>(float v) { return __float2bfloat16(v); }

__device__ inline void gload_lds16(const bf16* g, bf16* l) {
    __builtin_amdgcn_global_load_lds(
        (const __attribute__((address_space(1))) void*)g,
        (__attribute__((address_space(3))) void*)l, 16, 0, 0);
}

// ---- fused fp32->bf16 convert for x + 6 weights, one launch ----
struct CvtPack {
    const float* src[7];
    bf16* dst[7];
    int end[7];   // cumulative element ends
};

__global__ __launch_bounds__(256) void cvt_all(CvtPack p) {
    int e = (blockIdx.x * 256 + threadIdx.x) * 4;
    int start = 0;
#pragma unroll
    for (int s = 0; s < 7; ++s) {
        if (e < p.end[s]) {
            int off = e - start;
            float4 v = *(const float4*)(p.src[s] + off);
            bf16* d = p.dst[s] + off;
            d[0] = __float2bfloat16(v.x);
            d[1] = __float2bfloat16(v.y);
            d[2] = __float2bfloat16(v.z);
            d[3] = __float2bfloat16(v.w);
            return;
        }
        start = p.end[s];
    }
}

// out = p0 + p1 + bias (split-K reduction). N power of two (nmask = N-1).
// p1 MUST be p0 + M*N (the PARTIAL gemm writes chunk y at C + y*M*N).
__global__ __launch_bounds__(256) void reduce2_bias(const float* __restrict__ p0,
                                                    const float* __restrict__ p1,
                                                    const float* __restrict__ bias,
                                                    float* __restrict__ out,
                                                    int nmask, int total4) {
    int i = blockIdx.x * 256 + threadIdx.x;
    if (i < total4) {
        int idx = i * 4;
        float4 a = *(const float4*)(p0 + idx);
        float4 b = *(const float4*)(p1 + idx);
        float4 bb = *(const float4*)(bias + (idx & nmask));
        float4 r;
        r.x = a.x + b.x + bb.x;
        r.y = a.y + b.y + bb.y;
        r.z = a.z + b.z + bb.z;
        r.w = a.w + b.w + bb.w;
        *(float4*)(out + idx) = r;
    }
}

// C[m][n] = act( sum_k A[m][k] * W[n][k] + bias[n] )
// ACT: 0=none, 1=relu, 2=tanh. Tile = (32*WMT) x (32*WNT), 4 waves 2x2.
// XCD swizzle on blockIdx.x: all bn-tiles of one bm land on one XCD (L2 A-reuse).
// PARTIAL: split-K — blockIdx.y selects K-chunk [y*kcount, (y+1)*kcount), raw
// fp32 partial written to C + y*M*N (no bias/act).
template <int ACT, typename OutT, int WMT, int WNT, int BKT, bool PARTIAL>
__global__ __launch_bounds__(256) void gemm_bt(const bf16* __restrict__ A,
                                               const bf16* __restrict__ W,
                                               const float* __restrict__ bias,
                                               OutT* __restrict__ C,
                                               int M, int N, int K,
                                               int nbn, int kcount) {
    constexpr int TBM = 32 * WMT;
    constexpr int TBN = 32 * WNT;
    constexpr int CPR = BKT / 8;          // 16B chunks per tile row
    constexpr int CA = TBM * CPR;
    constexpr int CB = TBN * CPR;

    __shared__ bf16 As[TBM * BKT];
    __shared__ bf16 Bs[TBN * BKT];

    const int bi = blockIdx.x;
    const int xcd = bi & 7, t = bi >> 3;
    const int bn = t % nbn;
    const int bm = xcd + 8 * (t / nbn);   // bm % 8 == xcd for all bn of this bm
    const int kbeg = PARTIAL ? blockIdx.y * kcount : 0;
    OutT* Cp = PARTIAL ? C + (size_t)blockIdx.y * M * N : C;

    const int tid = threadIdx.x;
    const int wave = tid >> 6, lane = tid & 63;
    const int wm = (wave >> 1) * (16 * WMT), wn = (wave & 1) * (16 * WNT);
    const int quad = lane >> 4, lrow = lane & 15;

    float4v acc[WMT][WNT] = {};
    const size_t arow = (size_t)(bm * TBM) * K;
    const size_t brow = (size_t)(bn * TBN) * K;

    for (int k0 = kbeg; k0 < kbeg + kcount; k0 += BKT) {
        __syncthreads();  // protect LDS from previous iteration's readers
#pragma unroll
        for (int tt = 0; tt < CA / 256; ++tt) {
            int base = tt * 256 + wave * 64;       // wave-uniform
            int c = base + lane;
            int row = c / CPR, col = (c % CPR) * 8;
            gload_lds16(A + arow + (size_t)row * K + k0 + col, As + base * 8);
        }
#pragma unroll
        for (int tt = 0; tt < CB / 256; ++tt) {
            int base = tt * 256 + wave * 64;
            int c = base + lane;
            int row = c / CPR, col = (c % CPR) * 8;
            gload_lds16(W + brow + (size_t)row * K + k0 + col, Bs + base * 8);
        }
        __syncthreads();  // drains the async loads (vmcnt(0)) + barrier
#pragma unroll
        for (int kk = 0; kk < BKT; kk += 32) {
            short8 af[WMT], bfr[WNT];
#pragma unroll
            for (int i = 0; i < WMT; ++i)
                af[i] = *(const short8*)(As + (wm + i * 16 + lrow) * BKT + kk + quad * 8);
#pragma unroll
            for (int j = 0; j < WNT; ++j)
                bfr[j] = *(const short8*)(Bs + (wn + j * 16 + lrow) * BKT + kk + quad * 8);
#pragma unroll
            for (int i = 0; i < WMT; ++i)
#pragma unroll
                for (int j = 0; j < WNT; ++j)
                    acc[i][j] = __builtin_amdgcn_mfma_f32_16x16x32_bf16(af[i], bfr[j], acc[i][j], 0, 0, 0);
        }
    }

    // epilogue: C/D layout col=lane&15, row=quad*4+reg (m89/m91-verified)
#pragma unroll
    for (int i = 0; i < WMT; ++i) {
        int m0 = bm * TBM + wm + i * 16 + quad * 4;
#pragma unroll
        for (int j = 0; j < WNT; ++j) {
            int n = bn * TBN + wn + j * 16 + lrow;
            if constexpr (PARTIAL) {
#pragma unroll
                for (int r = 0; r < 4; ++r)
                    Cp[(size_t)(m0 + r) * N + n] = acc[i][j][r];
            } else {
                float bv = bias[n];
#pragma unroll
                for (int r = 0; r < 4; ++r) {
                    float v = acc[i][j][r] + bv;
                    if (ACT == 1) v = fmaxf(v, 0.f);
                    else if (ACT == 2) v = tanhf(v);
                    Cp[(size_t)(m0 + r) * N + n] = cvt_out<OutT>(v);
                }
            }
        }
    }
}

// One wave per row: power-norm -> single-tap channel + noise -> LS h_est -> ZF.
__global__ __launch_bounds__(64) void channel_kernel(const float* __restrict__ s,
                                                     const float* __restrict__ h,
                                                     const float* __restrict__ noise,
                                                     float* __restrict__ xr_f,
                                                     bf16* __restrict__ xr_b) {
    const int b = blockIdx.x, lane = threadIdx.x;
    const float* srow = s + (size_t)b * 256;

    float ss = 0.f;
#pragma unroll
    for (int t = 0; t < 4; ++t) {
        float v = srow[lane + 64 * t];
        ss += v * v;
    }
#pragma unroll
    for (int off = 32; off; off >>= 1) ss += __shfl_xor(ss, off);
    const float inv = sqrtf(128.0f) / sqrtf(ss);  // sqrt(2n*0.5) / ||s||

    const float hre = h[0], him = h[1];

    float yre[2], yim[2];
    float nre = 0.f, nim = 0.f, den = 0.f;
#pragma unroll
    for (int t = 0; t < 2; ++t) {
        int c = lane + 64 * t;
        float tr = srow[2 * c] * inv, ti = srow[2 * c + 1] * inv;
        float yr = hre * tr - him * ti + noise[(size_t)b * 256 + 2 * c];
        float yi = hre * ti + him * tr + noise[(size_t)b * 256 + 2 * c + 1];
        yre[t] = yr; yim[t] = yi;
        nre += yr * tr + yi * ti;
        nim += yi * tr - yr * ti;
        den += tr * tr + ti * ti;
    }
#pragma unroll
    for (int off = 32; off; off >>= 1) {
        nre += __shfl_xor(nre, off);
        nim += __shfl_xor(nim, off);
        den += __shfl_xor(den, off);
    }
    const float her = nre / den, hei = nim / den;
    const float d2 = her * her + hei * hei + 1e-12f;

#pragma unroll
    for (int t = 0; t < 2; ++t) {
        int c = lane + 64 * t;
        float xre = (yre[t] * her + yim[t] * hei) / d2;
        float xim = (yim[t] * her - yre[t] * hei) / d2;
        xr_f[(size_t)b * 256 + 2 * c] = xre;
        xr_f[(size_t)b * 256 + 2 * c + 1] = xim;
        xr_b[(size_t)b * 256 + 2 * c] = __float2bfloat16(xre);
        xr_b[(size_t)b * 256 + 2 * c + 1] = __float2bfloat16(xim);
    }
}

// One wave per row: h_inv = g2 @ w_rtn3^T + b_rtn3 (N=6), 3-tap complex FIR.
__global__ __launch_bounds__(64) void rtn_taps_conv(const bf16* __restrict__ g2,
                                                    const float* __restrict__ wr3,
                                                    const float* __restrict__ br3,
                                                    const float* __restrict__ xr_f,
                                                    bf16* __restrict__ xr2) {
    const int b = blockIdx.x, lane = threadIdx.x;
    const bf16* grow = g2 + (size_t)b * 1024;

    float acc[6] = {0.f, 0.f, 0.f, 0.f, 0.f, 0.f};
#pragma unroll
    for (int t = 0; t < 16; ++t) {
        int k = lane + 64 * t;
        float gv = __bfloat162float(grow[k]);
#pragma unroll
        for (int j = 0; j < 6; ++j) acc[j] += gv * wr3[j * 1024 + k];
    }
#pragma unroll
    for (int j = 0; j < 6; ++j)
#pragma unroll
        for (int off = 32; off; off >>= 1) acc[j] += __shfl_xor(acc[j], off);

    float tre[3], tim[3];
#pragma unroll
    for (int l = 0; l < 3; ++l) {
        tre[l] = acc[2 * l] + br3[2 * l];
        tim[l] = acc[2 * l + 1] + br3[2 * l + 1];
    }

    const float* xrow = xr_f + (size_t)b * 256;
#pragma unroll
    for (int t = 0; t < 2; ++t) {
        int c = lane + 64 * t;
        float ore = 0.f, oim = 0.f;
#pragma unroll
        for (int l = 0; l < 3; ++l) {
            int cc = c - l;
            if (cc >= 0) {
                float xre = xrow[2 * cc], xim = xrow[2 * cc + 1];
                ore += tre[l] * xre - tim[l] * xim;
                oim += tre[l] * xim + tim[l] * xre;
            }
        }
        xr2[(size_t)b * 256 + 2 * c] = __float2bfloat16(ore);
        xr2[(size_t)b * 256 + 2 * c + 1] = __float2bfloat16(oim);
    }
}

extern "C" void kernel_launch(void* const* d_in, const int* in_sizes, int n_in,
                              void* d_out, int out_size, void* d_ws, size_t ws_size,
                              hipStream_t stream) {
    constexpr int B = 8192, D_IN = 512, H1 = 4096, CH = 256, HR = 1024, H2 = 4096, DOUT = 512;

    const float* x   = (const float*)d_in[0];
    const float* w1  = (const float*)d_in[1];
    const float* b1  = (const float*)d_in[2];
    const float* w2  = (const float*)d_in[3];
    const float* b2  = (const float*)d_in[4];
    const float* wr1 = (const float*)d_in[5];
    const float* br1 = (const float*)d_in[6];
    const float* wr2 = (const float*)d_in[7];
    const float* br2 = (const float*)d_in[8];
    const float* wr3 = (const float*)d_in[9];
    const float* br3 = (const float*)d_in[10];
    const float* w3  = (const float*)d_in[11];
    const float* b3  = (const float*)d_in[12];
    const float* w4  = (const float*)d_in[13];
    const float* b4  = (const float*)d_in[14];
    const float* h   = (const float*)d_in[15];
    const float* noise = (const float*)d_in[16];

    // ---- workspace layout (bytes), peak ~116 MB ----
    char* ws = (char*)d_ws;
    bf16*  a    = (bf16*)(ws + 0);          // 64 MB: GEMM1 out; later: g1 | tbuf
    bf16*  g1   = (bf16*)(ws + 0);          // 16 MB (a dead after GEMM2)
    bf16*  g2   = (bf16*)(ws + 16777216);   // 16 MB
    bf16*  tbuf = (bf16*)(ws + 0);          // 64 MB (g1/g2 dead after rtn_taps_conv)
    bf16*  xB   = (bf16*)(ws + 67108864);               // 8 MB  bf16(x), dead after G1
    float* sF   = (float*)(ws + 75497472);              // 8 MB
    float* xrF  = (float*)(ws + 83886080);              // 8 MB
    bf16*  xrB  = (bf16*)(ws + 92274688);               // 4 MB
    bf16*  xr2  = (bf16*)(ws + 96468992);               // 4 MB
    bf16*  w1B  = (bf16*)(ws + 100663296);              // 4 MB
    bf16*  w2B  = (bf16*)(ws + 104857600);              // 2 MB
    bf16*  wr1B = (bf16*)(ws + 106954752);              // 0.5 MB
    bf16*  wr2B = (bf16*)(ws + 107479040);              // 2 MB
    bf16*  w3B  = (bf16*)(ws + 109576192);              // 2 MB
    bf16*  w4B  = (bf16*)(ws + 111673344);              // 4 MB -> ends ~115.9 MB

    // split-K partial buffers. The PARTIAL gemm writes chunk y at C + y*M*N,
    // so the two partials are CONTIGUOUS from the base pointer:
    // G2: M*N*4 = 8 MB -> base ws+83886080, y=1 auto at ws+92274688
    //     (covers xrF/xrB/xr2 — all dead until channel_kernel, which runs
    //     after reduce2_bias consumes the partials).  [R6 bug: base was
    //     ws+67108864 so y=1 landed on sF while reduce read ws+83886080.]
    float* g2P = (float*)(ws + 83886080);
    // G6: M*N*4 = 16 MB -> base ws+67108864, y=1 auto at ws+83886080 (all dead).
    float* g6P = (float*)(ws + 67108864);

    dim3 blk(256);

    // ---- single fused fp32->bf16 convert ----
    CvtPack p;
    const float* srcs[7] = {x, w1, w2, wr1, wr2, w3, w4};
    bf16* dsts[7] = {xB, w1B, w2B, wr1B, wr2B, w3B, w4B};
    int ns[7] = {B * D_IN, H1 * D_IN, CH * H1, HR * CH, HR * HR, H2 * CH, DOUT * H2};
    int cum = 0;
    for (int i = 0; i < 7; ++i) { p.src[i] = srcs[i]; p.dst[i] = dsts[i]; cum += ns[i]; p.end[i] = cum; }
    cvt_all<<<(cum / 4 + 255) / 256, blk, 0, stream>>>(p);

    // ---- encoder ----
    // G1: 128x128, BK=64, nbm=64, nbn=32, grid 2048
    gemm_bt<1, bf16, 4, 4, 64, false><<<64 * 32, blk, 0, stream>>>(
        xB, w1B, b1, a, B, H1, D_IN, 32, D_IN);
    // G2: 64x64, BK=128, split-K=2 (2048 each) -> grid 1024 (4 blocks/CU)
    gemm_bt<0, float, 2, 2, 128, true><<<dim3(128 * 4, 2), blk, 0, stream>>>(
        a, w2B, nullptr, g2P, B, CH, H1, 4, H1 / 2);
    reduce2_bias<<<(B * CH / 4 + 255) / 256, blk, 0, stream>>>(
        g2P, g2P + (size_t)B * CH, b2, sF, CH - 1, B * CH / 4);
    // ---- channel + ZF (fp32) ----
    channel_kernel<<<B, 64, 0, stream>>>(sF, h, noise, xrF, xrB);
    // ---- RTN ----
    // G3: 128x64, BK=64, nbm=64, nbn=16, grid 1024
    gemm_bt<2, bf16, 4, 2, 64, false><<<64 * 16, blk, 0, stream>>>(
        xrB, wr1B, br1, g1, B, HR, CH, 16, CH);
    // G4: 128x64, BK=64, nbm=64, nbn=16, grid 1024
    gemm_bt<2, bf16, 4, 2, 64, false><<<64 * 16, blk, 0, stream>>>(
        g1, wr2B, br2, g2, B, HR, HR, 16, HR);
    rtn_taps_conv<<<B, 64, 0, stream>>>(g2, wr3, br3, xrF, xr2);
    // ---- decoder ----
    // G5: 128x128, BK=64, nbm=64, nbn=32, grid 2048
    gemm_bt<1, bf16, 4, 4, 64, false><<<64 * 32, blk, 0, stream>>>(
        xr2, w3B, b3, tbuf, B, H2, CH, 32, CH);
    // G6: 128x64, BK=64 (LDS 24KB -> 4+ blocks/CU), split-K=2 -> grid 1024
    gemm_bt<0, float, 4, 2, 64, true><<<dim3(64 * 8, 2), blk, 0, stream>>>(
        tbuf, w4B, nullptr, g6P, B, DOUT, H2, 8, H2 / 2);
    reduce2_bias<<<(B * DOUT / 4 + 255) / 256, blk, 0, stream>>>(
        g6P, g6P + (size_t)B * DOUT, b4, (float*)d_out, DOUT - 1, B * DOUT / 4);
}

// Round 8
// 387.888 us; speedup vs baseline: 1.2460x; 1.0694x over previous
//
#include <hip/hip_runtime.h>
#include <hip/hip_bf16.h>
#include <math.h>

using bf16 = __hip_bfloat16;
typedef __attribute__((ext_vector_type(8))) short short8;
typedef __attribute__((ext_vector_type(4))) float float4v;

template <typename T> __device__ inline T cvt_out(float v);
template <> __device__ inline float cvt_out<float>(float v) { return v; }
template <> __device__ inline bf16 cvt_out<bf16>(float v) { return __float2bfloat16(v); }

__device__ inline void gload_lds16(const bf16* g, bf16* l) {
    __builtin_amdgcn_global_load_lds(
        (const __attribute__((address_space(1))) void*)g,
        (__attribute__((address_space(3))) void*)l, 16, 0, 0);
}

// ---- fused fp32->bf16 convert for x + 6 weights, one launch ----
struct CvtPack {
    const float* src[7];
    bf16* dst[7];
    int end[7];   // cumulative element ends
};

__global__ __launch_bounds__(256) void cvt_all(CvtPack p) {
    int e = (blockIdx.x * 256 + threadIdx.x) * 4;
    int start = 0;
#pragma unroll
    for (int s = 0; s < 7; ++s) {
        if (e < p.end[s]) {
            int off = e - start;
            float4 v = *(const float4*)(p.src[s] + off);
            bf16* d = p.dst[s] + off;
            d[0] = __float2bfloat16(v.x);
            d[1] = __float2bfloat16(v.y);
            d[2] = __float2bfloat16(v.z);
            d[3] = __float2bfloat16(v.w);
            return;
        }
        start = p.end[s];
    }
}

// out = sum_k p[k*mn ..] + bias. In-place safe if out aliases one partial
// (each thread reads all partials at idx before storing idx).
template <int NK>
__global__ __launch_bounds__(256) void reduceK_bias(const float* __restrict__ p,
                                                    const float* __restrict__ bias,
                                                    float* __restrict__ out,
                                                    size_t mn, int nmask, int total4) {
    int i = blockIdx.x * 256 + threadIdx.x;
    if (i < total4) {
        int idx = i * 4;
        float4 bb = *(const float4*)(bias + (idx & nmask));
        float4 r = bb;
#pragma unroll
        for (int k = 0; k < NK; ++k) {
            float4 a = *(const float4*)(p + k * mn + idx);
            r.x += a.x; r.y += a.y; r.z += a.z; r.w += a.w;
        }
        *(float4*)(out + idx) = r;
    }
}

// C[m][n] = act( sum_k A[m][k] * W[n][k] + bias[n] )
// ACT: 0=none, 1=relu, 2=tanh. Tile = (32*WMT) x (32*WNT), 4 waves 2x2.
// XCD swizzle: all bn-tiles of one bm land on one XCD (L2 A-reuse).
// PARTIAL: split-K — blockIdx.y -> K-chunk, raw fp32 partial at C + y*M*N.
// Epilogue repacks acc through LDS so global stores are 16B/lane coalesced.
template <int ACT, typename OutT, int WMT, int WNT, int BKT, bool PARTIAL>
__global__ __launch_bounds__(256) void gemm_bt(const bf16* __restrict__ A,
                                               const bf16* __restrict__ W,
                                               const float* __restrict__ bias,
                                               OutT* __restrict__ C,
                                               int M, int N, int K,
                                               int nbn, int kcount) {
    constexpr int TBM = 32 * WMT;
    constexpr int TBN = 32 * WNT;
    constexpr int CPR = BKT / 8;          // 16B chunks per tile row
    constexpr int CA = TBM * CPR;
    constexpr int CB = TBN * CPR;
    constexpr int STAGE_B = (TBM + TBN) * BKT * 2;
    constexpr int REPACK_B = TBM * TBN * (int)sizeof(OutT);
    constexpr int SH = STAGE_B > REPACK_B ? STAGE_B : REPACK_B;

    __shared__ __align__(16) char smem[SH];
    bf16* As = (bf16*)smem;
    bf16* Bs = As + TBM * BKT;

    const int bi = blockIdx.x;
    const int xcd = bi & 7, t = bi >> 3;
    const int bn = t % nbn;
    const int bm = xcd + 8 * (t / nbn);   // bm % 8 == xcd for all bn of this bm
    const int kbeg = PARTIAL ? blockIdx.y * kcount : 0;
    OutT* Cp = PARTIAL ? C + (size_t)blockIdx.y * M * N : C;

    const int tid = threadIdx.x;
    const int wave = tid >> 6, lane = tid & 63;
    const int wm = (wave >> 1) * (16 * WMT), wn = (wave & 1) * (16 * WNT);
    const int quad = lane >> 4, lrow = lane & 15;

    float4v acc[WMT][WNT] = {};
    const size_t arow = (size_t)(bm * TBM) * K;
    const size_t brow = (size_t)(bn * TBN) * K;

    for (int k0 = kbeg; k0 < kbeg + kcount; k0 += BKT) {
        __syncthreads();  // protect LDS from previous iteration's readers
#pragma unroll
        for (int tt = 0; tt < CA / 256; ++tt) {
            int base = tt * 256 + wave * 64;       // wave-uniform
            int c = base + lane;
            int row = c / CPR, col = (c % CPR) * 8;
            gload_lds16(A + arow + (size_t)row * K + k0 + col, As + base * 8);
        }
#pragma unroll
        for (int tt = 0; tt < CB / 256; ++tt) {
            int base = tt * 256 + wave * 64;
            int c = base + lane;
            int row = c / CPR, col = (c % CPR) * 8;
            gload_lds16(W + brow + (size_t)row * K + k0 + col, Bs + base * 8);
        }
        __syncthreads();  // drains the async loads (vmcnt(0)) + barrier
#pragma unroll
        for (int kk = 0; kk < BKT; kk += 32) {
            short8 af[WMT], bfr[WNT];
#pragma unroll
            for (int i = 0; i < WMT; ++i)
                af[i] = *(const short8*)(As + (wm + i * 16 + lrow) * BKT + kk + quad * 8);
#pragma unroll
            for (int j = 0; j < WNT; ++j)
                bfr[j] = *(const short8*)(Bs + (wn + j * 16 + lrow) * BKT + kk + quad * 8);
#pragma unroll
            for (int i = 0; i < WMT; ++i)
#pragma unroll
                for (int j = 0; j < WNT; ++j)
                    acc[i][j] = __builtin_amdgcn_mfma_f32_16x16x32_bf16(af[i], bfr[j], acc[i][j], 0, 0, 0);
        }
    }

    // ---- epilogue: bias/act, repack via LDS, coalesced 16B stores ----
    // C/D layout col=lane&15, row=quad*4+reg (m89/m91-verified)
    __syncthreads();  // all MFMA fragment reads done; LDS reusable
    OutT* R = (OutT*)smem;
#pragma unroll
    for (int i = 0; i < WMT; ++i) {
        int row0 = wm + i * 16 + quad * 4;
#pragma unroll
        for (int j = 0; j < WNT; ++j) {
            int col = wn + j * 16 + lrow;
            float bv = 0.f;
            if constexpr (!PARTIAL) bv = bias[bn * TBN + col];
#pragma unroll
            for (int r = 0; r < 4; ++r) {
                float v = acc[i][j][r] + bv;
                if constexpr (!PARTIAL) {
                    if (ACT == 1) v = fmaxf(v, 0.f);
                    else if (ACT == 2) v = tanhf(v);
                }
                R[(row0 + r) * TBN + col] = cvt_out<OutT>(v);
            }
        }
    }
    __syncthreads();
    constexpr int EPC = 16 / (int)sizeof(OutT);   // elems per 16B chunk
    constexpr int CR = TBN / EPC;                 // chunks per output row
    constexpr int TOT = TBM * CR;
#pragma unroll
    for (int t2 = 0; t2 < TOT / 256; ++t2) {
        int c = t2 * 256 + tid;
        int row = c / CR, cin = c % CR;
        float4 v = *((const float4*)smem + c);
        *(float4*)&Cp[(size_t)(bm * TBM + row) * N + bn * TBN + cin * EPC] = v;
    }
}

// One wave per row: power-norm -> single-tap channel + noise -> LS h_est -> ZF.
__global__ __launch_bounds__(64) void channel_kernel(const float* __restrict__ s,
                                                     const float* __restrict__ h,
                                                     const float* __restrict__ noise,
                                                     float* __restrict__ xr_f,
                                                     bf16* __restrict__ xr_b) {
    const int b = blockIdx.x, lane = threadIdx.x;
    const float* srow = s + (size_t)b * 256;

    float ss = 0.f;
#pragma unroll
    for (int t = 0; t < 4; ++t) {
        float v = srow[lane + 64 * t];
        ss += v * v;
    }
#pragma unroll
    for (int off = 32; off; off >>= 1) ss += __shfl_xor(ss, off);
    const float inv = sqrtf(128.0f) / sqrtf(ss);  // sqrt(2n*0.5) / ||s||

    const float hre = h[0], him = h[1];

    float yre[2], yim[2];
    float nre = 0.f, nim = 0.f, den = 0.f;
#pragma unroll
    for (int t = 0; t < 2; ++t) {
        int c = lane + 64 * t;
        float tr = srow[2 * c] * inv, ti = srow[2 * c + 1] * inv;
        float yr = hre * tr - him * ti + noise[(size_t)b * 256 + 2 * c];
        float yi = hre * ti + him * tr + noise[(size_t)b * 256 + 2 * c + 1];
        yre[t] = yr; yim[t] = yi;
        nre += yr * tr + yi * ti;
        nim += yi * tr - yr * ti;
        den += tr * tr + ti * ti;
    }
#pragma unroll
    for (int off = 32; off; off >>= 1) {
        nre += __shfl_xor(nre, off);
        nim += __shfl_xor(nim, off);
        den += __shfl_xor(den, off);
    }
    const float her = nre / den, hei = nim / den;
    const float d2 = her * her + hei * hei + 1e-12f;

#pragma unroll
    for (int t = 0; t < 2; ++t) {
        int c = lane + 64 * t;
        float xre = (yre[t] * her + yim[t] * hei) / d2;
        float xim = (yim[t] * her - yre[t] * hei) / d2;
        xr_f[(size_t)b * 256 + 2 * c] = xre;
        xr_f[(size_t)b * 256 + 2 * c + 1] = xim;
        xr_b[(size_t)b * 256 + 2 * c] = __float2bfloat16(xre);
        xr_b[(size_t)b * 256 + 2 * c + 1] = __float2bfloat16(xim);
    }
}

// One wave per row: h_inv = g2 @ w_rtn3^T + b_rtn3 (N=6), 3-tap complex FIR.
__global__ __launch_bounds__(64) void rtn_taps_conv(const bf16* __restrict__ g2,
                                                    const float* __restrict__ wr3,
                                                    const float* __restrict__ br3,
                                                    const float* __restrict__ xr_f,
                                                    bf16* __restrict__ xr2) {
    const int b = blockIdx.x, lane = threadIdx.x;
    const bf16* grow = g2 + (size_t)b * 1024;

    float acc[6] = {0.f, 0.f, 0.f, 0.f, 0.f, 0.f};
#pragma unroll
    for (int t = 0; t < 16; ++t) {
        int k = lane + 64 * t;
        float gv = __bfloat162float(grow[k]);
#pragma unroll
        for (int j = 0; j < 6; ++j) acc[j] += gv * wr3[j * 1024 + k];
    }
#pragma unroll
    for (int j = 0; j < 6; ++j)
#pragma unroll
        for (int off = 32; off; off >>= 1) acc[j] += __shfl_xor(acc[j], off);

    float tre[3], tim[3];
#pragma unroll
    for (int l = 0; l < 3; ++l) {
        tre[l] = acc[2 * l] + br3[2 * l];
        tim[l] = acc[2 * l + 1] + br3[2 * l + 1];
    }

    const float* xrow = xr_f + (size_t)b * 256;
#pragma unroll
    for (int t = 0; t < 2; ++t) {
        int c = lane + 64 * t;
        float ore = 0.f, oim = 0.f;
#pragma unroll
        for (int l = 0; l < 3; ++l) {
            int cc = c - l;
            if (cc >= 0) {
                float xre = xrow[2 * cc], xim = xrow[2 * cc + 1];
                ore += tre[l] * xre - tim[l] * xim;
                oim += tre[l] * xim + tim[l] * xre;
            }
        }
        xr2[(size_t)b * 256 + 2 * c] = __float2bfloat16(ore);
        xr2[(size_t)b * 256 + 2 * c + 1] = __float2bfloat16(oim);
    }
}

extern "C" void kernel_launch(void* const* d_in, const int* in_sizes, int n_in,
                              void* d_out, int out_size, void* d_ws, size_t ws_size,
                              hipStream_t stream) {
    constexpr int B = 8192, D_IN = 512, H1 = 4096, CH = 256, HR = 1024, H2 = 4096, DOUT = 512;

    const float* x   = (const float*)d_in[0];
    const float* w1  = (const float*)d_in[1];
    const float* b1  = (const float*)d_in[2];
    const float* w2  = (const float*)d_in[3];
    const float* b2  = (const float*)d_in[4];
    const float* wr1 = (const float*)d_in[5];
    const float* br1 = (const float*)d_in[6];
    const float* wr2 = (const float*)d_in[7];
    const float* br2 = (const float*)d_in[8];
    const float* wr3 = (const float*)d_in[9];
    const float* br3 = (const float*)d_in[10];
    const float* w3  = (const float*)d_in[11];
    const float* b3  = (const float*)d_in[12];
    const float* w4  = (const float*)d_in[13];
    const float* b4  = (const float*)d_in[14];
    const float* h   = (const float*)d_in[15];
    const float* noise = (const float*)d_in[16];

    // ---- workspace layout (bytes), peak 115.9 MB (same footprint as R2-R7) ----
    char* ws = (char*)d_ws;
    bf16*  a    = (bf16*)(ws + 0);          // 64 MB: G1 out; later: g1 | g2 | tbuf
    bf16*  g1   = (bf16*)(ws + 0);          // 16 MB (a dead after G2)
    bf16*  g2   = (bf16*)(ws + 16777216);   // 16 MB
    bf16*  tbuf = (bf16*)(ws + 0);          // 64 MB (g1/g2 dead after rtn_taps_conv)
    bf16*  w1B  = (bf16*)(ws + 67108864);   // 4 MB
    bf16*  w2B  = (bf16*)(ws + 71303168);   // 2 MB
    bf16*  wr1B = (bf16*)(ws + 73400320);   // 0.5 MB
    bf16*  wr2B = (bf16*)(ws + 73924608);   // 2 MB
    bf16*  w3B  = (bf16*)(ws + 76021760);   // 2 MB
    bf16*  w4B  = (bf16*)(ws + 78118912);   // 4 MB
    bf16*  xB   = (bf16*)(ws + 82313216);   // 8 MB  bf16(x), dead after G1
    float* sF   = (float*)(ws + 90701824);  // 8 MB
    float* xrF  = (float*)(ws + 99090432);  // 8 MB
    bf16*  xrB  = (bf16*)(ws + 107479040);  // 4 MB
    bf16*  xr2  = (bf16*)(ws + 111673344);  // 4 MB -> ends 115867648

    // split-K partials (contiguous, stride M*N; kernel writes chunk y at C+y*M*N)
    // G2: 4 x 8 MB at 82313216..115867648 (xB dead; sF = partial#1 region is
    //     the reduce OUTPUT — in-place elementwise safe; xrF/xrB/xr2 written
    //     later by channel_kernel).
    float* g2P = (float*)(ws + 82313216);
    // G6: 2 x 16 MB at 82313216..115867648 (entire window dead at G6 time).
    float* g6P = (float*)(ws + 82313216);

    dim3 blk(256);

    // ---- single fused fp32->bf16 convert ----
    CvtPack p;
    const float* srcs[7] = {x, w1, w2, wr1, wr2, w3, w4};
    bf16* dsts[7] = {xB, w1B, w2B, wr1B, wr2B, w3B, w4B};
    int ns[7] = {B * D_IN, H1 * D_IN, CH * H1, HR * CH, HR * HR, H2 * CH, DOUT * H2};
    int cum = 0;
    for (int i = 0; i < 7; ++i) { p.src[i] = srcs[i]; p.dst[i] = dsts[i]; cum += ns[i]; p.end[i] = cum; }
    cvt_all<<<(cum / 4 + 255) / 256, blk, 0, stream>>>(p);

    // ---- encoder ----
    // G1: 128x128, BK=64, nbm=64, nbn=32, grid 2048
    gemm_bt<1, bf16, 4, 4, 64, false><<<64 * 32, blk, 0, stream>>>(
        xB, w1B, b1, a, B, H1, D_IN, 32, D_IN);
    // G2: 128x64, BK=64, split-K=4 (1024 each) -> grid 1024 (4 blocks/CU)
    gemm_bt<0, float, 4, 2, 64, true><<<dim3(64 * 4, 4), blk, 0, stream>>>(
        a, w2B, nullptr, g2P, B, CH, H1, 4, H1 / 4);
    reduceK_bias<4><<<(B * CH / 4 + 255) / 256, blk, 0, stream>>>(
        g2P, b2, sF, (size_t)B * CH, CH - 1, B * CH / 4);
    // ---- channel + ZF (fp32) ----
    channel_kernel<<<B, 64, 0, stream>>>(sF, h, noise, xrF, xrB);
    // ---- RTN ----
    // G3: 128x64, BK=64, nbm=64, nbn=16, grid 1024
    gemm_bt<2, bf16, 4, 2, 64, false><<<64 * 16, blk, 0, stream>>>(
        xrB, wr1B, br1, g1, B, HR, CH, 16, CH);
    // G4: 128x64, BK=64, nbm=64, nbn=16, grid 1024
    gemm_bt<2, bf16, 4, 2, 64, false><<<64 * 16, blk, 0, stream>>>(
        g1, wr2B, br2, g2, B, HR, HR, 16, HR);
    rtn_taps_conv<<<B, 64, 0, stream>>>(g2, wr3, br3, xrF, xr2);
    // ---- decoder ----
    // G5: 128x128, BK=64, nbm=64, nbn=32, grid 2048
    gemm_bt<1, bf16, 4, 4, 64, false><<<64 * 32, blk, 0, stream>>>(
        xr2, w3B, b3, tbuf, B, H2, CH, 32, CH);
    // G6: 128x64, BK=64, split-K=2 -> grid 1024
    gemm_bt<0, float, 4, 2, 64, true><<<dim3(64 * 8, 2), blk, 0, stream>>>(
        tbuf, w4B, nullptr, g6P, B, DOUT, H2, 8, H2 / 2);
    reduceK_bias<2><<<(B * DOUT / 4 + 255) / 256, blk, 0, stream>>>(
        g6P, b4, (float*)d_out, (size_t)B * DOUT, DOUT - 1, B * DOUT / 4);
}

// Round 9
// 369.202 us; speedup vs baseline: 1.3091x; 1.0506x over previous
//
#include <hip/hip_runtime.h>
#include <hip/hip_bf16.h>
#include <math.h>

using bf16 = __hip_bfloat16;
typedef __attribute__((ext_vector_type(8))) short short8;
typedef __attribute__((ext_vector_type(4))) float float4v;

template <typename T> __device__ inline T cvt_out(float v);
template <> __device__ inline float cvt_out<float>(float v) { return v; }
template <> __device__ inline bf16 cvt_out<bf16>(float v) { return __float2bfloat16(v); }

__device__ inline void gload_lds16(const bf16* g, bf16* l) {
    __builtin_amdgcn_global_load_lds(
        (const __attribute__((address_space(1))) void*)g,
        (__attribute__((address_space(3))) void*)l, 16, 0, 0);
}

// ---- fused fp32->bf16 convert for x + 6 weights, one launch ----
struct CvtPack {
    const float* src[7];
    bf16* dst[7];
    int end[7];   // cumulative element ends
};

__global__ __launch_bounds__(256) void cvt_all(CvtPack p) {
    int e = (blockIdx.x * 256 + threadIdx.x) * 4;
    int start = 0;
#pragma unroll
    for (int s = 0; s < 7; ++s) {
        if (e < p.end[s]) {
            int off = e - start;
            float4 v = *(const float4*)(p.src[s] + off);
            bf16* d = p.dst[s] + off;
            d[0] = __float2bfloat16(v.x);
            d[1] = __float2bfloat16(v.y);
            d[2] = __float2bfloat16(v.z);
            d[3] = __float2bfloat16(v.w);
            return;
        }
        start = p.end[s];
    }
}

// out = sum_k p[k*mn ..] + bias. In-place safe if out aliases one partial.
template <int NK>
__global__ __launch_bounds__(256) void reduceK_bias(const float* __restrict__ p,
                                                    const float* __restrict__ bias,
                                                    float* __restrict__ out,
                                                    size_t mn, int nmask, int total4) {
    int i = blockIdx.x * 256 + threadIdx.x;
    if (i < total4) {
        int idx = i * 4;
        float4 bb = *(const float4*)(bias + (idx & nmask));
        float4 r = bb;
#pragma unroll
        for (int k = 0; k < NK; ++k) {
            float4 a = *(const float4*)(p + k * mn + idx);
            r.x += a.x; r.y += a.y; r.z += a.z; r.w += a.w;
        }
        *(float4*)(out + idx) = r;
    }
}

// ---- 256-thread GEMM: tile (32*WMT)x(32*WNT), 4 waves 2x2, direct stores ----
// C[m][n] = act( sum_k A[m][k]*W[n][k] + bias[n] ); XCD swizzle on 1D grid.
// PARTIAL: split-K, blockIdx.y -> chunk, fp32 partial at C + y*M*N.
template <int ACT, typename OutT, int WMT, int WNT, int BKT, bool PARTIAL>
__global__ __launch_bounds__(256) void gemm_bt(const bf16* __restrict__ A,
                                               const bf16* __restrict__ W,
                                               const float* __restrict__ bias,
                                               OutT* __restrict__ C,
                                               int M, int N, int K,
                                               int nbn, int kcount) {
    constexpr int TBM = 32 * WMT;
    constexpr int TBN = 32 * WNT;
    constexpr int CPR = BKT / 8;
    constexpr int CA = TBM * CPR;
    constexpr int CB = TBN * CPR;

    __shared__ bf16 As[TBM * BKT];
    __shared__ bf16 Bs[TBN * BKT];

    const int bi = blockIdx.x;
    const int xcd = bi & 7, t = bi >> 3;
    const int bn = t % nbn;
    const int bm = xcd + 8 * (t / nbn);
    const int kbeg = PARTIAL ? blockIdx.y * kcount : 0;
    OutT* Cp = PARTIAL ? C + (size_t)blockIdx.y * M * N : C;

    const int tid = threadIdx.x;
    const int wave = tid >> 6, lane = tid & 63;
    const int wm = (wave >> 1) * (16 * WMT), wn = (wave & 1) * (16 * WNT);
    const int quad = lane >> 4, lrow = lane & 15;

    float4v acc[WMT][WNT] = {};
    const size_t arow = (size_t)(bm * TBM) * K;
    const size_t brow = (size_t)(bn * TBN) * K;

    for (int k0 = kbeg; k0 < kbeg + kcount; k0 += BKT) {
        __syncthreads();
#pragma unroll
        for (int tt = 0; tt < CA / 256; ++tt) {
            int base = tt * 256 + wave * 64;       // wave-uniform
            int c = base + lane;
            int row = c / CPR, col = (c % CPR) * 8;
            gload_lds16(A + arow + (size_t)row * K + k0 + col, As + base * 8);
        }
#pragma unroll
        for (int tt = 0; tt < CB / 256; ++tt) {
            int base = tt * 256 + wave * 64;
            int c = base + lane;
            int row = c / CPR, col = (c % CPR) * 8;
            gload_lds16(W + brow + (size_t)row * K + k0 + col, Bs + base * 8);
        }
        __syncthreads();
#pragma unroll
        for (int kk = 0; kk < BKT; kk += 32) {
            short8 af[WMT], bfr[WNT];
#pragma unroll
            for (int i = 0; i < WMT; ++i)
                af[i] = *(const short8*)(As + (wm + i * 16 + lrow) * BKT + kk + quad * 8);
#pragma unroll
            for (int j = 0; j < WNT; ++j)
                bfr[j] = *(const short8*)(Bs + (wn + j * 16 + lrow) * BKT + kk + quad * 8);
#pragma unroll
            for (int i = 0; i < WMT; ++i)
#pragma unroll
                for (int j = 0; j < WNT; ++j)
                    acc[i][j] = __builtin_amdgcn_mfma_f32_16x16x32_bf16(af[i], bfr[j], acc[i][j], 0, 0, 0);
        }
    }

    // direct-store epilogue (R7 style; R8's LDS repack measured -4% -> reverted)
#pragma unroll
    for (int i = 0; i < WMT; ++i) {
        int m0 = bm * TBM + wm + i * 16 + quad * 4;
#pragma unroll
        for (int j = 0; j < WNT; ++j) {
            int n = bn * TBN + wn + j * 16 + lrow;
            if constexpr (PARTIAL) {
#pragma unroll
                for (int r = 0; r < 4; ++r)
                    Cp[(size_t)(m0 + r) * N + n] = acc[i][j][r];
            } else {
                float bv = bias[n];
#pragma unroll
                for (int r = 0; r < 4; ++r) {
                    float v = acc[i][j][r] + bv;
                    if (ACT == 1) v = fmaxf(v, 0.f);
                    else if (ACT == 2) v = tanhf(v);
                    Cp[(size_t)(m0 + r) * N + n] = cvt_out<OutT>(v);
                }
            }
        }
    }
}

// ---- 512-thread GEMM: tile 256x128, 8 waves 4x2, per-wave 64x64 ----
// Cuts staged-bytes/FLOP 25% vs 128x128 for the big-M GEMMs (G1/G5).
template <int ACT, typename OutT>
__global__ __launch_bounds__(512, 4) void gemm_bt_wide(const bf16* __restrict__ A,
                                                       const bf16* __restrict__ W,
                                                       const float* __restrict__ bias,
                                                       OutT* __restrict__ C,
                                                       int M, int N, int K,
                                                       int nbn) {
    constexpr int TBM = 256, TBN = 128, BKT = 64;
    constexpr int CPR = BKT / 8;          // 8 chunks per row
    constexpr int CA = TBM * CPR;         // 2048
    constexpr int CB = TBN * CPR;         // 1024

    __shared__ bf16 As[TBM * BKT];        // 32 KB
    __shared__ bf16 Bs[TBN * BKT];        // 16 KB

    const int bi = blockIdx.x;
    const int xcd = bi & 7, t = bi >> 3;
    const int bn = t % nbn;
    const int bm = xcd + 8 * (t / nbn);

    const int tid = threadIdx.x;
    const int wave = tid >> 6, lane = tid & 63;
    const int wm = (wave >> 1) * 64, wn = (wave & 1) * 64;   // 4x2 wave grid
    const int quad = lane >> 4, lrow = lane & 15;

    float4v acc[4][4] = {};
    const size_t arow = (size_t)(bm * TBM) * K;
    const size_t brow = (size_t)(bn * TBN) * K;

    for (int k0 = 0; k0 < K; k0 += BKT) {
        __syncthreads();
#pragma unroll
        for (int tt = 0; tt < CA / 512; ++tt) {   // 4 iters
            int base = tt * 512 + wave * 64;
            int c = base + lane;
            int row = c / CPR, col = (c % CPR) * 8;
            gload_lds16(A + arow + (size_t)row * K + k0 + col, As + base * 8);
        }
#pragma unroll
        for (int tt = 0; tt < CB / 512; ++tt) {   // 2 iters
            int base = tt * 512 + wave * 64;
            int c = base + lane;
            int row = c / CPR, col = (c % CPR) * 8;
            gload_lds16(W + brow + (size_t)row * K + k0 + col, Bs + base * 8);
        }
        __syncthreads();
#pragma unroll
        for (int kk = 0; kk < BKT; kk += 32) {
            short8 af[4], bfr[4];
#pragma unroll
            for (int i = 0; i < 4; ++i)
                af[i] = *(const short8*)(As + (wm + i * 16 + lrow) * BKT + kk + quad * 8);
#pragma unroll
            for (int j = 0; j < 4; ++j)
                bfr[j] = *(const short8*)(Bs + (wn + j * 16 + lrow) * BKT + kk + quad * 8);
#pragma unroll
            for (int i = 0; i < 4; ++i)
#pragma unroll
                for (int j = 0; j < 4; ++j)
                    acc[i][j] = __builtin_amdgcn_mfma_f32_16x16x32_bf16(af[i], bfr[j], acc[i][j], 0, 0, 0);
        }
    }

#pragma unroll
    for (int i = 0; i < 4; ++i) {
        int m0 = bm * TBM + wm + i * 16 + quad * 4;
#pragma unroll
        for (int j = 0; j < 4; ++j) {
            int n = bn * TBN + wn + j * 16 + lrow;
            float bv = bias[n];
#pragma unroll
            for (int r = 0; r < 4; ++r) {
                float v = acc[i][j][r] + bv;
                if (ACT == 1) v = fmaxf(v, 0.f);
                else if (ACT == 2) v = tanhf(v);
                C[(size_t)(m0 + r) * N + n] = cvt_out<OutT>(v);
            }
        }
    }
}

// One wave per row: power-norm -> single-tap channel + noise -> LS h_est -> ZF.
__global__ __launch_bounds__(64) void channel_kernel(const float* __restrict__ s,
                                                     const float* __restrict__ h,
                                                     const float* __restrict__ noise,
                                                     float* __restrict__ xr_f,
                                                     bf16* __restrict__ xr_b) {
    const int b = blockIdx.x, lane = threadIdx.x;
    const float* srow = s + (size_t)b * 256;

    float ss = 0.f;
#pragma unroll
    for (int t = 0; t < 4; ++t) {
        float v = srow[lane + 64 * t];
        ss += v * v;
    }
#pragma unroll
    for (int off = 32; off; off >>= 1) ss += __shfl_xor(ss, off);
    const float inv = sqrtf(128.0f) / sqrtf(ss);

    const float hre = h[0], him = h[1];

    float yre[2], yim[2];
    float nre = 0.f, nim = 0.f, den = 0.f;
#pragma unroll
    for (int t = 0; t < 2; ++t) {
        int c = lane + 64 * t;
        float tr = srow[2 * c] * inv, ti = srow[2 * c + 1] * inv;
        float yr = hre * tr - him * ti + noise[(size_t)b * 256 + 2 * c];
        float yi = hre * ti + him * tr + noise[(size_t)b * 256 + 2 * c + 1];
        yre[t] = yr; yim[t] = yi;
        nre += yr * tr + yi * ti;
        nim += yi * tr - yr * ti;
        den += tr * tr + ti * ti;
    }
#pragma unroll
    for (int off = 32; off; off >>= 1) {
        nre += __shfl_xor(nre, off);
        nim += __shfl_xor(nim, off);
        den += __shfl_xor(den, off);
    }
    const float her = nre / den, hei = nim / den;
    const float d2 = her * her + hei * hei + 1e-12f;

#pragma unroll
    for (int t = 0; t < 2; ++t) {
        int c = lane + 64 * t;
        float xre = (yre[t] * her + yim[t] * hei) / d2;
        float xim = (yim[t] * her - yre[t] * hei) / d2;
        xr_f[(size_t)b * 256 + 2 * c] = xre;
        xr_f[(size_t)b * 256 + 2 * c + 1] = xim;
        xr_b[(size_t)b * 256 + 2 * c] = __float2bfloat16(xre);
        xr_b[(size_t)b * 256 + 2 * c + 1] = __float2bfloat16(xim);
    }
}

// One wave per row: h_inv = g2 @ w_rtn3^T + b_rtn3 (N=6), 3-tap complex FIR.
__global__ __launch_bounds__(64) void rtn_taps_conv(const bf16* __restrict__ g2,
                                                    const float* __restrict__ wr3,
                                                    const float* __restrict__ br3,
                                                    const float* __restrict__ xr_f,
                                                    bf16* __restrict__ xr2) {
    const int b = blockIdx.x, lane = threadIdx.x;
    const bf16* grow = g2 + (size_t)b * 1024;

    float acc[6] = {0.f, 0.f, 0.f, 0.f, 0.f, 0.f};
#pragma unroll
    for (int t = 0; t < 16; ++t) {
        int k = lane + 64 * t;
        float gv = __bfloat162float(grow[k]);
#pragma unroll
        for (int j = 0; j < 6; ++j) acc[j] += gv * wr3[j * 1024 + k];
    }
#pragma unroll
    for (int j = 0; j < 6; ++j)
#pragma unroll
        for (int off = 32; off; off >>= 1) acc[j] += __shfl_xor(acc[j], off);

    float tre[3], tim[3];
#pragma unroll
    for (int l = 0; l < 3; ++l) {
        tre[l] = acc[2 * l] + br3[2 * l];
        tim[l] = acc[2 * l + 1] + br3[2 * l + 1];
    }

    const float* xrow = xr_f + (size_t)b * 256;
#pragma unroll
    for (int t = 0; t < 2; ++t) {
        int c = lane + 64 * t;
        float ore = 0.f, oim = 0.f;
#pragma unroll
        for (int l = 0; l < 3; ++l) {
            int cc = c - l;
            if (cc >= 0) {
                float xre = xrow[2 * cc], xim = xrow[2 * cc + 1];
                ore += tre[l] * xre - tim[l] * xim;
                oim += tre[l] * xim + tim[l] * xre;
            }
        }
        xr2[(size_t)b * 256 + 2 * c] = __float2bfloat16(ore);
        xr2[(size_t)b * 256 + 2 * c + 1] = __float2bfloat16(oim);
    }
}

extern "C" void kernel_launch(void* const* d_in, const int* in_sizes, int n_in,
                              void* d_out, int out_size, void* d_ws, size_t ws_size,
                              hipStream_t stream) {
    constexpr int B = 8192, D_IN = 512, H1 = 4096, CH = 256, HR = 1024, H2 = 4096, DOUT = 512;

    const float* x   = (const float*)d_in[0];
    const float* w1  = (const float*)d_in[1];
    const float* b1  = (const float*)d_in[2];
    const float* w2  = (const float*)d_in[3];
    const float* b2  = (const float*)d_in[4];
    const float* wr1 = (const float*)d_in[5];
    const float* br1 = (const float*)d_in[6];
    const float* wr2 = (const float*)d_in[7];
    const float* br2 = (const float*)d_in[8];
    const float* wr3 = (const float*)d_in[9];
    const float* br3 = (const float*)d_in[10];
    const float* w3  = (const float*)d_in[11];
    const float* b3  = (const float*)d_in[12];
    const float* w4  = (const float*)d_in[13];
    const float* b4  = (const float*)d_in[14];
    const float* h   = (const float*)d_in[15];
    const float* noise = (const float*)d_in[16];

    // ---- workspace layout (bytes), peak 115.9 MB ----
    char* ws = (char*)d_ws;
    bf16*  a    = (bf16*)(ws + 0);          // 64 MB: G1 out; later: g1 | g2 | tbuf
    bf16*  g1   = (bf16*)(ws + 0);          // 16 MB
    bf16*  g2   = (bf16*)(ws + 16777216);   // 16 MB
    bf16*  tbuf = (bf16*)(ws + 0);          // 64 MB
    bf16*  w1B  = (bf16*)(ws + 67108864);   // 4 MB
    bf16*  w2B  = (bf16*)(ws + 71303168);   // 2 MB
    bf16*  wr1B = (bf16*)(ws + 73400320);   // 0.5 MB
    bf16*  wr2B = (bf16*)(ws + 73924608);   // 2 MB
    bf16*  w3B  = (bf16*)(ws + 76021760);   // 2 MB
    bf16*  w4B  = (bf16*)(ws + 78118912);   // 4 MB
    bf16*  xB   = (bf16*)(ws + 82313216);   // 8 MB, dead after G1
    float* sF   = (float*)(ws + 90701824);  // 8 MB
    float* xrF  = (float*)(ws + 99090432);  // 8 MB
    bf16*  xrB  = (bf16*)(ws + 107479040);  // 4 MB
    bf16*  xr2  = (bf16*)(ws + 111673344);  // 4 MB -> ends 115867648

    // split-K partials (contiguous, stride M*N from base):
    float* g2P = (float*)(ws + 82313216);   // 4 x 8 MB (xB dead; sF=out in-place ok)
    float* g6P = (float*)(ws + 82313216);   // 2 x 16 MB (window dead at G6 time)

    dim3 blk(256);

    // ---- single fused fp32->bf16 convert ----
    CvtPack p;
    const float* srcs[7] = {x, w1, w2, wr1, wr2, w3, w4};
    bf16* dsts[7] = {xB, w1B, w2B, wr1B, wr2B, w3B, w4B};
    int ns[7] = {B * D_IN, H1 * D_IN, CH * H1, HR * CH, HR * HR, H2 * CH, DOUT * H2};
    int cum = 0;
    for (int i = 0; i < 7; ++i) { p.src[i] = srcs[i]; p.dst[i] = dsts[i]; cum += ns[i]; p.end[i] = cum; }
    cvt_all<<<(cum / 4 + 255) / 256, blk, 0, stream>>>(p);

    // ---- encoder ----
    // G1: 256x128 wide tile, nbm=32, nbn=32, grid 1024 x 512thr (2 blocks/CU)
    gemm_bt_wide<1, bf16><<<32 * 32, dim3(512), 0, stream>>>(
        xB, w1B, b1, a, B, H1, D_IN, 32);
    // G2: 128x64, BK=64, split-K=4 -> grid 1024 (4 blocks/CU)
    gemm_bt<0, float, 4, 2, 64, true><<<dim3(64 * 4, 4), blk, 0, stream>>>(
        a, w2B, nullptr, g2P, B, CH, H1, 4, H1 / 4);
    reduceK_bias<4><<<(B * CH / 4 + 255) / 256, blk, 0, stream>>>(
        g2P, b2, sF, (size_t)B * CH, CH - 1, B * CH / 4);
    // ---- channel + ZF (fp32) ----
    channel_kernel<<<B, 64, 0, stream>>>(sF, h, noise, xrF, xrB);
    // ---- RTN ----
    // G3: 128x64, BK=64, nbm=64, nbn=16, grid 1024
    gemm_bt<2, bf16, 4, 2, 64, false><<<64 * 16, blk, 0, stream>>>(
        xrB, wr1B, br1, g1, B, HR, CH, 16, CH);
    // G4: 128x64, BK=64, nbm=64, nbn=16, grid 1024
    gemm_bt<2, bf16, 4, 2, 64, false><<<64 * 16, blk, 0, stream>>>(
        g1, wr2B, br2, g2, B, HR, HR, 16, HR);
    rtn_taps_conv<<<B, 64, 0, stream>>>(g2, wr3, br3, xrF, xr2);
    // ---- decoder ----
    // G5: 256x128 wide tile, nbm=32, nbn=32, grid 1024 x 512thr
    gemm_bt_wide<1, bf16><<<32 * 32, dim3(512), 0, stream>>>(
        xr2, w3B, b3, tbuf, B, H2, CH, 32);
    // G6: 128x64, BK=64, split-K=2 -> grid 1024
    gemm_bt<0, float, 4, 2, 64, true><<<dim3(64 * 8, 2), blk, 0, stream>>>(
        tbuf, w4B, nullptr, g6P, B, DOUT, H2, 8, H2 / 2);
    reduceK_bias<2><<<(B * DOUT / 4 + 255) / 256, blk, 0, stream>>>(
        g6P, b4, (float*)d_out, (size_t)B * DOUT, DOUT - 1, B * DOUT / 4);
}